// Round 3
// baseline (418.101 us; speedup 1.0000x reference)
//
#include <hip/hip_runtime.h>
#include <cmath>

// b=4, c=512, h=w=64 -> n=4096, groups=32 (16 ch/group)
#define NB 4
#define NC 512
#define NN 4096
#define ATTN_SCALE 0.04419417382415922f  // 512^-0.5

typedef __bf16 bf16x8 __attribute__((ext_vector_type(8)));
typedef float floatx4 __attribute__((ext_vector_type(4)));

__device__ __forceinline__ unsigned short f2bf(float f) {
    union { float f; unsigned int u; } v; v.f = f;
    return (unsigned short)((v.u + 0x7fffu + ((v.u >> 16) & 1u)) >> 16);
}
__device__ __forceinline__ unsigned short f2bf_trunc(float f) {
    union { float f; unsigned int u; } v; v.f = f;
    return (unsigned short)(v.u >> 16);
}

__device__ __forceinline__ void gload_lds16(const unsigned short* gp, unsigned short* lp) {
    __builtin_amdgcn_global_load_lds(
        (const __attribute__((address_space(1))) void*)gp,
        (__attribute__((address_space(3))) void*)lp, 16, 0, 0);
}

template<int N> __device__ __forceinline__ void wait_vmcnt() {
    if constexpr (N == 0) asm volatile("s_waitcnt vmcnt(0)" ::: "memory");
    else if constexpr (N == 3) asm volatile("s_waitcnt vmcnt(3)" ::: "memory");
    else if constexpr (N == 4) asm volatile("s_waitcnt vmcnt(4)" ::: "memory");
    else if constexpr (N == 6) asm volatile("s_waitcnt vmcnt(6)" ::: "memory");
}

// ---------------------------------------------------------------------------
// Kernel 1a: GroupNorm partial sums. 1024 blocks = (b,g) x 8 slices.
// ---------------------------------------------------------------------------
__global__ __launch_bounds__(256) void gn_partial_kernel(
    const float* __restrict__ x, float* __restrict__ part)
{
    int blk = blockIdx.x;
    int bg = blk >> 3, sub = blk & 7;
    const float4* xv = (const float4*)(x + (size_t)bg * 16 * NN + (size_t)sub * 8192);
    float s1 = 0.f, s2 = 0.f;
#pragma unroll
    for (int i = 0; i < 8; ++i) {
        float4 v = xv[threadIdx.x + i * 256];
        s1 += v.x + v.y + v.z + v.w;
        s2 += v.x * v.x + v.y * v.y + v.z * v.z + v.w * v.w;
    }
#pragma unroll
    for (int off = 32; off; off >>= 1) {
        s1 += __shfl_xor(s1, off, 64);
        s2 += __shfl_xor(s2, off, 64);
    }
    __shared__ float r1[4], r2[4];
    int lane = threadIdx.x & 63, w = threadIdx.x >> 6;
    if (lane == 0) { r1[w] = s1; r2[w] = s2; }
    __syncthreads();
    if (threadIdx.x == 0) {
        part[blk * 2]     = r1[0] + r1[1] + r1[2] + r1[3];
        part[blk * 2 + 1] = r2[0] + r2[1] + r2[2] + r2[3];
    }
}

// Kernel 1b: finalize -> per-channel scale/shift
__global__ __launch_bounds__(128) void gn_final_kernel(
    const float* __restrict__ part, const float* __restrict__ gw,
    const float* __restrict__ gb, float* __restrict__ ss)
{
    int tg = threadIdx.x;            // 0..127 = b*32+g
    int b = tg >> 5, g = tg & 31;
    float s1 = 0.f, s2 = 0.f;
#pragma unroll
    for (int s = 0; s < 8; ++s) {
        s1 += part[(tg * 8 + s) * 2];
        s2 += part[(tg * 8 + s) * 2 + 1];
    }
    float mean = s1 * (1.0f / 65536.0f);
    float var  = s2 * (1.0f / 65536.0f) - mean * mean;
    float rstd = rsqrtf(var + 1e-5f);
#pragma unroll
    for (int i = 0; i < 16; ++i) {
        int c = g * 16 + i;
        float sc = rstd * gw[c];
        ss[b * NC + c] = sc;
        ss[2048 + b * NC + c] = gb[c] - mean * sc;
    }
}

// ---------------------------------------------------------------------------
// Kernel 2: convert weights fp32 -> bf16
// ---------------------------------------------------------------------------
__global__ __launch_bounds__(256) void wconv_kernel(
    const float* __restrict__ qkv_w, const float* __restrict__ out_w,
    unsigned short* __restrict__ wq, unsigned short* __restrict__ wo)
{
    int i = blockIdx.x * 256 + threadIdx.x;
    const int NQ = 1536 * 512;
    if (i < NQ) wq[i] = f2bf(qkv_w[i]);
    else        wo[i - NQ] = f2bf(out_w[i - NQ]);
}

// ---------------------------------------------------------------------------
// Kernel 3: normalize + transpose: x (b,c,n) fp32 -> h_t (b,n,c) bf16
// ---------------------------------------------------------------------------
__global__ __launch_bounds__(256) void htnorm_kernel(
    const float* __restrict__ x, const float* __restrict__ ss,
    unsigned short* __restrict__ ht)
{
    int b = blockIdx.z;
    int c0 = blockIdx.y * 32, n0 = blockIdx.x * 32;
    __shared__ float T[32][33];
    int tx = threadIdx.x & 31, ty = threadIdx.x >> 5;   // ty 0..7
    const float* xb = x + ((size_t)b * NC + c0) * NN;
    const float* sc = ss + b * NC + c0;
    const float* sh = ss + 2048 + b * NC + c0;
#pragma unroll
    for (int i = 0; i < 4; ++i) {
        int c = ty + i * 8;
        T[c][tx] = xb[(size_t)c * NN + n0 + tx] * sc[c] + sh[c];
    }
    __syncthreads();
    unsigned short* hb = ht + ((size_t)b * NN + n0) * NC + c0;
#pragma unroll
    for (int i = 0; i < 4; ++i) {
        int n = ty + i * 8;
        hb[(size_t)n * NC + tx] = f2bf(T[tx][n]);
    }
}

// ---------------------------------------------------------------------------
// MFMA NT GEMM: C[m,n] = sum_k A[m,k]*B[n,k], BK=32 steps, row stride = KD.
// Round-3: counted-vmcnt multi-buffer pipeline (T4). NBUF buffers, DEPTH =
// NBUF-1 tiles in flight; per step: stage(t+DEPTH) -> compute(t) ->
// lgkmcnt(0) [protect LDS buffer reuse] -> vmcnt((DEPTH-1)*LPS) [tile t+1
// landed, DEPTH-1 tiles still in flight -- never drain to 0] -> raw s_barrier.
// MODE 2 additionally gets an XCD-aware decode: each XCD owns 16 m-rows of
// one batch (qt panels 2MB resident) with n-tile slow -> kt[z] fetched ~once
// per XCD; turns HBM-latency tile loads into L2 hits.
// MODE 0: qkv q/k   M=4096 N=1024 K=512  A=ht(+z) B=wqk    -> qt(*scale)/kt +bias
// MODE 1: qkv v     M=512  N=4096 K=512  A=wv     B=ht(+z) -> vt (c,p) bf16 +bias
// MODE 2: QK^T      M=4096 N=4096 K=512  A=qt(+z) B=kt(+z) -> SP = exp(s) bf16,
//                   row-sums atomically accumulated into e? -> outf = L[b*NN+row]
// MODE 4: out proj  M=512  N=4096 K=512  A=wo     B=Ob(+z) -> out fp32 +bias+res
// MODE 5: PV        M=256(p)x... A=SP(+z) (p,m) B=vt(+z) (c,m) KD=4096
//                   -> Ob[p,c] = acc / L[p]  (e0 = Lsum)
// ---------------------------------------------------------------------------
template<int MODE, int BM, int BN, int KD, int NBUF, int MINB>
__global__ __launch_bounds__(256, MINB) void mfma_gemm(
    const unsigned short* __restrict__ Abase,
    const unsigned short* __restrict__ Bbase,
    const float* __restrict__ e0, const float* __restrict__ e1,
    float* __restrict__ outf,
    unsigned short* __restrict__ ob0, unsigned short* __restrict__ ob1)
{
    constexpr int NT = KD / 32;
    constexpr int FI = BM / 32;       // frag rows per wave
    constexpr int FJ = BN / 32;       // frag cols per wave
    constexpr int LPS = BM / 64 + BN / 64;   // gloads per thread per stage
    constexpr int DEPTH = NBUF - 1;
    const size_t bnc = (size_t)NN * NC;
    const size_t bss = (size_t)NN * NN;

    int z, m0, n0;
    if constexpr (MODE == 2) {
        // XCD-grouped: xcd = id&7 (round-robin dispatch). Each XCD: 16 m-rows
        // (one half-batch), m-row fastest, n-tile slow.
        const int id = blockIdx.x;
        const int xcd = id & 7, j = id >> 3;       // j in [0,512)
        const int row = xcd * 16 + (j & 15);       // [0,128)
        z = row >> 5; m0 = (row & 31) * BM; n0 = (j >> 4) * BN;
    } else if constexpr (MODE == 5) {
        // 4 c-tiles of each (z,ptile) consecutive on one XCD (share SP panel)
        const int id = blockIdx.x;
        const int xcd = id & 7, j0 = id >> 3;      // j0 in [0,128)
        const int p = (j0 >> 2) * 8 + xcd;         // [0,256) bijective
        z = p >> 6; m0 = (p & 63) * BM; n0 = (j0 & 3) * BN;
    } else {
        z = blockIdx.z; m0 = blockIdx.y * BM; n0 = blockIdx.x * BN;
    }

    const unsigned short* A;
    const unsigned short* B;
    if constexpr (MODE == 0)      { A = Abase + (size_t)z * bnc; B = Bbase; }
    else if constexpr (MODE == 1) { A = Abase; B = Bbase + (size_t)z * bnc; }
    else if constexpr (MODE == 2) { A = Abase + (size_t)z * bnc; B = Bbase + (size_t)z * bnc; }
    else if constexpr (MODE == 5) { A = Abase + (size_t)z * bss; B = Bbase + (size_t)z * bnc; }
    else                          { A = Abase; B = Bbase + (size_t)z * bnc; }

    __shared__ __attribute__((aligned(16))) unsigned short As[NBUF][BM * 32];
    __shared__ __attribute__((aligned(16))) unsigned short Bs[NBUF][BN * 32];

    const int t = threadIdx.x;
    const int lane = t & 63;
    const int w = t >> 6;
    const int wr = w >> 1, wc = w & 1;

    // staging: one gload round = 256 threads x 16B = 64 rows x 32 cols.
    const int sr = w * 16 + (lane >> 2);                    // row in 64-row slab
    const int scs = ((lane & 3) ^ ((lane >> 3) & 3)) * 8;   // pre-swizzled col
    const int lds_elem = w * 512;
    const int kslot = lane >> 4;

    floatx4 acc[FI][FJ] = {};

    auto stage = [&](int buf, int tile) {
        const int k0 = tile * 32;
#pragma unroll
        for (int s = 0; s < BM / 64; ++s)
            gload_lds16(A + (size_t)(m0 + s * 64 + sr) * KD + k0 + scs,
                        &As[buf][s * 2048 + lds_elem]);
#pragma unroll
        for (int s = 0; s < BN / 64; ++s)
            gload_lds16(B + (size_t)(n0 + s * 64 + sr) * KD + k0 + scs,
                        &Bs[buf][s * 2048 + lds_elem]);
    };

    auto compute = [&](int buf) {
        bf16x8 af[FI], bfr[FJ];
#pragma unroll
        for (int i = 0; i < FI; ++i) {
            const int ra = wr * (BM / 2) + i * 16 + (lane & 15);
            af[i] = *(const bf16x8*)(&As[buf][ra * 32 + ((kslot ^ ((ra >> 1) & 3)) * 8)]);
        }
#pragma unroll
        for (int j = 0; j < FJ; ++j) {
            const int rb = wc * (BN / 2) + j * 16 + (lane & 15);
            bfr[j] = *(const bf16x8*)(&Bs[buf][rb * 32 + ((kslot ^ ((rb >> 1) & 3)) * 8)]);
        }
#pragma unroll
        for (int i = 0; i < FI; ++i)
#pragma unroll
            for (int j = 0; j < FJ; ++j)
                acc[i][j] = __builtin_amdgcn_mfma_f32_16x16x32_bf16(
                    af[i], bfr[j], acc[i][j], 0, 0, 0);
    };

    // ---- prologue: fill DEPTH tiles, wait for tile 0 only ----
#pragma unroll
    for (int d = 0; d < DEPTH; ++d) stage(d, d);
    wait_vmcnt<(DEPTH - 1) * LPS>();
    __builtin_amdgcn_s_barrier();

    // ---- main loop: counted vmcnt, never 0 ----
    if constexpr (NT <= 16) {
#pragma unroll
        for (int kt = 0; kt < NT - DEPTH; ++kt) {
            stage((kt + DEPTH) % NBUF, kt + DEPTH);
            compute(kt % NBUF);
            asm volatile("s_waitcnt lgkmcnt(0)" ::: "memory");
            wait_vmcnt<(DEPTH - 1) * LPS>();
            __builtin_amdgcn_s_barrier();
        }
    } else {
#pragma unroll 4
        for (int kt = 0; kt < NT - DEPTH; ++kt) {
            stage((kt + DEPTH) & (NBUF - 1), kt + DEPTH);   // NBUF pow2 here
            compute(kt & (NBUF - 1));
            asm volatile("s_waitcnt lgkmcnt(0)" ::: "memory");
            wait_vmcnt<(DEPTH - 1) * LPS>();
            __builtin_amdgcn_s_barrier();
        }
    }

    // ---- tail: drain remaining DEPTH tiles ----
    if constexpr (DEPTH == 2) {
        compute((NT - 2) % NBUF);
        asm volatile("s_waitcnt lgkmcnt(0)" ::: "memory");
        wait_vmcnt<0>();
        __builtin_amdgcn_s_barrier();
        compute((NT - 1) % NBUF);
    } else {   // DEPTH == 3
        compute((NT - 3) % NBUF);
        asm volatile("s_waitcnt lgkmcnt(0)" ::: "memory");
        wait_vmcnt<LPS>();
        __builtin_amdgcn_s_barrier();
        compute((NT - 2) % NBUF);
        asm volatile("s_waitcnt lgkmcnt(0)" ::: "memory");
        wait_vmcnt<0>();
        __builtin_amdgcn_s_barrier();
        compute((NT - 1) % NBUF);
    }

    // ---- Epilogue. C/D: col = lane&15, row = (lane>>4)*4 + reg ----
    const int fr = lane >> 4;
    const int fc = lane & 15;

    if constexpr (MODE == 2) {
        // exp + truncated bf16 store + per-row sum (16-lane reduce + atomicAdd)
        float rs[FI][4];
#pragma unroll
        for (int i = 0; i < FI; ++i)
#pragma unroll
            for (int r = 0; r < 4; ++r) rs[i][r] = 0.f;
#pragma unroll
        for (int i = 0; i < FI; ++i) {
#pragma unroll
            for (int j = 0; j < FJ; ++j) {
                int n = n0 + wc * (BN / 2) + j * 16 + fc;
                int mbase = m0 + wr * (BM / 2) + i * 16 + fr * 4;
#pragma unroll
                for (int r = 0; r < 4; ++r) {
                    float e = __expf(acc[i][j][r]);
                    ob0[(size_t)z * bss + (size_t)(mbase + r) * NN + n] = f2bf_trunc(e);
                    rs[i][r] += e;
                }
            }
        }
#pragma unroll
        for (int i = 0; i < FI; ++i) {
#pragma unroll
            for (int r = 0; r < 4; ++r) {
                float v = rs[i][r];
                v += __shfl_xor(v, 1, 16);
                v += __shfl_xor(v, 2, 16);
                v += __shfl_xor(v, 4, 16);
                v += __shfl_xor(v, 8, 16);
                if (fc == 0) {
                    int m = m0 + wr * (BM / 2) + i * 16 + fr * 4 + r;
                    atomicAdd(&outf[z * NN + m], v);
                }
            }
        }
        return;
    }

    if constexpr (MODE == 5) {
#pragma unroll
        for (int i = 0; i < FI; ++i) {
#pragma unroll
            for (int r = 0; r < 4; ++r) {
                int m = m0 + wr * (BM / 2) + i * 16 + fr * 4 + r;
                float linv = 1.0f / e0[z * NN + m];
#pragma unroll
                for (int j = 0; j < FJ; ++j) {
                    int n = n0 + wc * (BN / 2) + j * 16 + fc;
                    ob0[(size_t)z * bnc + (size_t)m * NC + n] = f2bf(acc[i][j][r] * linv);
                }
            }
        }
        return;
    }

#pragma unroll
    for (int i = 0; i < FI; ++i) {
#pragma unroll
        for (int j = 0; j < FJ; ++j) {
            int n = n0 + wc * (BN / 2) + j * 16 + fc;
            int mbase = m0 + wr * (BM / 2) + i * 16 + fr * 4;
#pragma unroll
            for (int r = 0; r < 4; ++r) {
                int m = mbase + r;
                float val = acc[i][j][r];
                if constexpr (MODE == 0) {
                    val += e0[n];   // qkv bias, o = n in [0,1024)
                    if (n < 512) ob0[((size_t)z * NN + m) * NC + n] = f2bf(val * ATTN_SCALE);
                    else         ob1[((size_t)z * NN + m) * NC + (n - 512)] = f2bf(val);
                } else if constexpr (MODE == 1) {
                    val += e0[1024 + m];   // v bias, channel = m
                    ob0[((size_t)z * NC + m) * NN + n] = f2bf(val);
                } else {   // MODE 4
                    size_t idx = ((size_t)z * NC + m) * NN + n;
                    outf[idx] = val + e0[m] + e1[idx];
                }
            }
        }
    }
}

// ---------------------------------------------------------------------------
extern "C" void kernel_launch(void* const* d_in, const int* in_sizes, int n_in,
                              void* d_out, int out_size, void* d_ws, size_t ws_size,
                              hipStream_t stream)
{
    const float* x     = (const float*)d_in[0];
    const float* gn_w  = (const float*)d_in[1];
    const float* gn_b  = (const float*)d_in[2];
    const float* qkv_w = (const float*)d_in[3];
    const float* qkv_b = (const float*)d_in[4];
    const float* out_w = (const float*)d_in[5];
    const float* out_b = (const float*)d_in[6];
    float* out = (float*)d_out;

    const size_t bnc = (size_t)NN * NC;          // 2,097,152 per batch
    char* w = (char*)d_ws;
    float* ss   = (float*)w;                 w += 16384;
    float* part = (float*)w;                 w += 8192;
    float* Lsum = (float*)w;                 w += (size_t)NB * NN * 4;  // row sums
    unsigned short* wq = (unsigned short*)w; w += (size_t)1536 * 512 * 2;
    unsigned short* wo = (unsigned short*)w; w += (size_t)512 * 512 * 2;
    unsigned short* qt = (unsigned short*)w; w += NB * bnc * 2;   // (b,n,c) pre-scaled
    unsigned short* kt = (unsigned short*)w; w += NB * bnc * 2;   // (b,n,c)
    unsigned short* vt = (unsigned short*)w; w += NB * bnc * 2;   // (b,c,n)
    unsigned short* SP = (unsigned short*)w; w += (size_t)NB * NN * NN * 2; // 128 MB
    // Aliases (lifetime-disjoint):
    unsigned short* ht = SP;   // ht (b,n,c) dead before MODE 2 writes SP
    unsigned short* Ob = qt;   // Ob (b,n,c) written after qt last read (MODE 2)

    hipMemsetAsync(Lsum, 0, (size_t)NB * NN * sizeof(float), stream);

    gn_partial_kernel<<<1024, 256, 0, stream>>>(x, part);
    gn_final_kernel<<<1, 128, 0, stream>>>(part, gn_w, gn_b, ss);
    wconv_kernel<<<(1536 * 512 + 512 * 512) / 256, 256, 0, stream>>>(qkv_w, out_w, wq, wo);
    htnorm_kernel<<<dim3(NN / 32, NC / 32, NB), 256, 0, stream>>>(x, ss, ht);

    // q/k: C[p,o] = ht · wqk^T   (q pre-scaled by ATTN_SCALE)
    mfma_gemm<0, 128, 128, 512, 3, 3><<<dim3(1024 / 128, NN / 128, NB), 256, 0, stream>>>(
        ht, wq, qkv_b, nullptr, nullptr, qt, kt);
    // v: C[c,p] = wv · ht^T   (64x128 tile -> 1024 blocks = 4/CU)
    mfma_gemm<1, 64, 128, 512, 3, 4><<<dim3(NN / 128, 512 / 64, NB), 256, 0, stream>>>(
        wq + (size_t)1024 * 512, ht, qkv_b, nullptr, nullptr, vt, nullptr);

    // QK^T + exp + row-sum accumulation; 1-D grid, XCD-decoded inside
    mfma_gemm<2, 128, 128, 512, 3, 3><<<dim3(4096), 256, 0, stream>>>(
        qt, kt, nullptr, nullptr, Lsum, SP, nullptr);
    // PV + normalize; KD=4096, 4 buffers 3-deep, XCD-decoded inside
    mfma_gemm<5, 64, 128, 4096, 4, 3><<<dim3(1024), 256, 0, stream>>>(
        SP, vt, Lsum, nullptr, nullptr, Ob, nullptr);

    // out projection + bias + residual (64x128 tile -> 1024 blocks = 4/CU)
    mfma_gemm<4, 64, 128, 512, 3, 4><<<dim3(NN / 128, 512 / 64, NB), 256, 0, stream>>>(
        wo, Ob, out_b, x, out, nullptr, nullptr);
}

// Round 4
// 369.376 us; speedup vs baseline: 1.1319x; 1.1319x over previous
//
#include <hip/hip_runtime.h>
#include <cmath>

// b=4, c=512, h=w=64 -> n=4096, groups=32 (16 ch/group)
#define NB 4
#define NC 512
#define NN 4096
#define ATTN_SCALE 0.04419417382415922f  // 512^-0.5

typedef __bf16 bf16x8 __attribute__((ext_vector_type(8)));
typedef float floatx4 __attribute__((ext_vector_type(4)));

__device__ __forceinline__ unsigned short f2bf(float f) {
    union { float f; unsigned int u; } v; v.f = f;
    return (unsigned short)((v.u + 0x7fffu + ((v.u >> 16) & 1u)) >> 16);
}
__device__ __forceinline__ unsigned short f2bf_trunc(float f) {
    union { float f; unsigned int u; } v; v.f = f;
    return (unsigned short)(v.u >> 16);
}

__device__ __forceinline__ void gload_lds16(const unsigned short* gp, unsigned short* lp) {
    __builtin_amdgcn_global_load_lds(
        (const __attribute__((address_space(1))) void*)gp,
        (__attribute__((address_space(3))) void*)lp, 16, 0, 0);
}

template<int N> __device__ __forceinline__ void wait_vmcnt() {
    if constexpr (N == 0) asm volatile("s_waitcnt vmcnt(0)" ::: "memory");
    else if constexpr (N == 3) asm volatile("s_waitcnt vmcnt(3)" ::: "memory");
    else if constexpr (N == 4) asm volatile("s_waitcnt vmcnt(4)" ::: "memory");
    else if constexpr (N == 6) asm volatile("s_waitcnt vmcnt(6)" ::: "memory");
}

// ---------------------------------------------------------------------------
// Kernel 1a: GroupNorm partial sums. 1024 blocks = (b,g) x 8 slices.
// ---------------------------------------------------------------------------
__global__ __launch_bounds__(256) void gn_partial_kernel(
    const float* __restrict__ x, float* __restrict__ part)
{
    int blk = blockIdx.x;
    int bg = blk >> 3, sub = blk & 7;
    const float4* xv = (const float4*)(x + (size_t)bg * 16 * NN + (size_t)sub * 8192);
    float s1 = 0.f, s2 = 0.f;
#pragma unroll
    for (int i = 0; i < 8; ++i) {
        float4 v = xv[threadIdx.x + i * 256];
        s1 += v.x + v.y + v.z + v.w;
        s2 += v.x * v.x + v.y * v.y + v.z * v.z + v.w * v.w;
    }
#pragma unroll
    for (int off = 32; off; off >>= 1) {
        s1 += __shfl_xor(s1, off, 64);
        s2 += __shfl_xor(s2, off, 64);
    }
    __shared__ float r1[4], r2[4];
    int lane = threadIdx.x & 63, w = threadIdx.x >> 6;
    if (lane == 0) { r1[w] = s1; r2[w] = s2; }
    __syncthreads();
    if (threadIdx.x == 0) {
        part[blk * 2]     = r1[0] + r1[1] + r1[2] + r1[3];
        part[blk * 2 + 1] = r2[0] + r2[1] + r2[2] + r2[3];
    }
}

// Kernel 1b: finalize -> per-channel scale/shift
__global__ __launch_bounds__(128) void gn_final_kernel(
    const float* __restrict__ part, const float* __restrict__ gw,
    const float* __restrict__ gb, float* __restrict__ ss)
{
    int tg = threadIdx.x;            // 0..127 = b*32+g
    int b = tg >> 5, g = tg & 31;
    float s1 = 0.f, s2 = 0.f;
#pragma unroll
    for (int s = 0; s < 8; ++s) {
        s1 += part[(tg * 8 + s) * 2];
        s2 += part[(tg * 8 + s) * 2 + 1];
    }
    float mean = s1 * (1.0f / 65536.0f);
    float var  = s2 * (1.0f / 65536.0f) - mean * mean;
    float rstd = rsqrtf(var + 1e-5f);
#pragma unroll
    for (int i = 0; i < 16; ++i) {
        int c = g * 16 + i;
        float sc = rstd * gw[c];
        ss[b * NC + c] = sc;
        ss[2048 + b * NC + c] = gb[c] - mean * sc;
    }
}

// ---------------------------------------------------------------------------
// Kernel 2: convert weights fp32 -> bf16
// ---------------------------------------------------------------------------
__global__ __launch_bounds__(256) void wconv_kernel(
    const float* __restrict__ qkv_w, const float* __restrict__ out_w,
    unsigned short* __restrict__ wq, unsigned short* __restrict__ wo)
{
    int i = blockIdx.x * 256 + threadIdx.x;
    const int NQ = 1536 * 512;
    if (i < NQ) wq[i] = f2bf(qkv_w[i]);
    else        wo[i - NQ] = f2bf(out_w[i - NQ]);
}

// ---------------------------------------------------------------------------
// Kernel 3: normalize + transpose: x (b,c,n) fp32 -> h_t (b,n,c) bf16
// ---------------------------------------------------------------------------
__global__ __launch_bounds__(256) void htnorm_kernel(
    const float* __restrict__ x, const float* __restrict__ ss,
    unsigned short* __restrict__ ht)
{
    int b = blockIdx.z;
    int c0 = blockIdx.y * 32, n0 = blockIdx.x * 32;
    __shared__ float T[32][33];
    int tx = threadIdx.x & 31, ty = threadIdx.x >> 5;   // ty 0..7
    const float* xb = x + ((size_t)b * NC + c0) * NN;
    const float* sc = ss + b * NC + c0;
    const float* sh = ss + 2048 + b * NC + c0;
#pragma unroll
    for (int i = 0; i < 4; ++i) {
        int c = ty + i * 8;
        T[c][tx] = xb[(size_t)c * NN + n0 + tx] * sc[c] + sh[c];
    }
    __syncthreads();
    unsigned short* hb = ht + ((size_t)b * NN + n0) * NC + c0;
#pragma unroll
    for (int i = 0; i < 4; ++i) {
        int n = ty + i * 8;
        hb[(size_t)n * NC + tx] = f2bf(T[tx][n]);
    }
}

// ---------------------------------------------------------------------------
// MFMA NT GEMM (projections): C[m,n] = sum_k A[m,k]*B[n,k], BK=32, KD=512.
// Counted-vmcnt multi-buffer pipeline (NBUF=3, DEPTH=2).
// MODE 0: qkv q/k   M=4096 N=1024 K=512  A=ht(+z) B=wqk    -> qt(*scale)/kt +bias
// MODE 1: qkv v     M=512  N=4096 K=512  A=wv     B=ht(+z) -> vt (c,p) bf16 +bias
// MODE 4: out proj  M=512  N=4096 K=512  A=wo     B=Ob(+z) -> out fp32 +bias+res
// ---------------------------------------------------------------------------
template<int MODE, int BM, int BN, int KD, int NBUF, int MINB>
__global__ __launch_bounds__(256, MINB) void mfma_gemm(
    const unsigned short* __restrict__ Abase,
    const unsigned short* __restrict__ Bbase,
    const float* __restrict__ e0, const float* __restrict__ e1,
    float* __restrict__ outf,
    unsigned short* __restrict__ ob0, unsigned short* __restrict__ ob1)
{
    constexpr int NT = KD / 32;
    constexpr int FI = BM / 32;       // frag rows per wave
    constexpr int FJ = BN / 32;       // frag cols per wave
    constexpr int LPS = BM / 64 + BN / 64;   // gloads per thread per stage
    constexpr int DEPTH = NBUF - 1;
    const size_t bnc = (size_t)NN * NC;

    const int z = blockIdx.z;
    const int m0 = blockIdx.y * BM;
    const int n0 = blockIdx.x * BN;

    const unsigned short* A;
    const unsigned short* B;
    if constexpr (MODE == 0)      { A = Abase + (size_t)z * bnc; B = Bbase; }
    else if constexpr (MODE == 1) { A = Abase; B = Bbase + (size_t)z * bnc; }
    else                          { A = Abase; B = Bbase + (size_t)z * bnc; }

    __shared__ __attribute__((aligned(16))) unsigned short As[NBUF][BM * 32];
    __shared__ __attribute__((aligned(16))) unsigned short Bs[NBUF][BN * 32];

    const int t = threadIdx.x;
    const int lane = t & 63;
    const int w = t >> 6;
    const int wr = w >> 1, wc = w & 1;

    // staging: one gload round = 256 threads x 16B = 64 rows x 32 cols.
    const int sr = w * 16 + (lane >> 2);                    // row in 64-row slab
    const int scs = ((lane & 3) ^ ((lane >> 3) & 3)) * 8;   // pre-swizzled col
    const int lds_elem = w * 512;
    const int kslot = lane >> 4;

    floatx4 acc[FI][FJ] = {};

    auto stage = [&](int buf, int tile) {
        const int k0 = tile * 32;
#pragma unroll
        for (int s = 0; s < BM / 64; ++s)
            gload_lds16(A + (size_t)(m0 + s * 64 + sr) * KD + k0 + scs,
                        &As[buf][s * 2048 + lds_elem]);
#pragma unroll
        for (int s = 0; s < BN / 64; ++s)
            gload_lds16(B + (size_t)(n0 + s * 64 + sr) * KD + k0 + scs,
                        &Bs[buf][s * 2048 + lds_elem]);
    };

    auto compute = [&](int buf) {
        bf16x8 af[FI], bfr[FJ];
#pragma unroll
        for (int i = 0; i < FI; ++i) {
            const int ra = wr * (BM / 2) + i * 16 + (lane & 15);
            af[i] = *(const bf16x8*)(&As[buf][ra * 32 + ((kslot ^ ((ra >> 1) & 3)) * 8)]);
        }
#pragma unroll
        for (int j = 0; j < FJ; ++j) {
            const int rb = wc * (BN / 2) + j * 16 + (lane & 15);
            bfr[j] = *(const bf16x8*)(&Bs[buf][rb * 32 + ((kslot ^ ((rb >> 1) & 3)) * 8)]);
        }
#pragma unroll
        for (int i = 0; i < FI; ++i)
#pragma unroll
            for (int j = 0; j < FJ; ++j)
                acc[i][j] = __builtin_amdgcn_mfma_f32_16x16x32_bf16(
                    af[i], bfr[j], acc[i][j], 0, 0, 0);
    };

    // ---- prologue: fill DEPTH tiles, wait for tile 0 only ----
#pragma unroll
    for (int d = 0; d < DEPTH; ++d) stage(d, d);
    wait_vmcnt<(DEPTH - 1) * LPS>();
    __builtin_amdgcn_s_barrier();

#pragma unroll
    for (int kt = 0; kt < NT - DEPTH; ++kt) {
        stage((kt + DEPTH) % NBUF, kt + DEPTH);
        compute(kt % NBUF);
        asm volatile("s_waitcnt lgkmcnt(0)" ::: "memory");
        wait_vmcnt<(DEPTH - 1) * LPS>();
        __builtin_amdgcn_s_barrier();
    }

    // ---- tail: drain remaining DEPTH(=2) tiles ----
    compute((NT - 2) % NBUF);
    asm volatile("s_waitcnt lgkmcnt(0)" ::: "memory");
    wait_vmcnt<0>();
    __builtin_amdgcn_s_barrier();
    compute((NT - 1) % NBUF);

    // ---- Epilogue. C/D: col = lane&15, row = (lane>>4)*4 + reg ----
    const int fr = lane >> 4;
    const int fc = lane & 15;

#pragma unroll
    for (int i = 0; i < FI; ++i) {
#pragma unroll
        for (int j = 0; j < FJ; ++j) {
            int n = n0 + wc * (BN / 2) + j * 16 + fc;
            int mbase = m0 + wr * (BM / 2) + i * 16 + fr * 4;
#pragma unroll
            for (int r = 0; r < 4; ++r) {
                int m = mbase + r;
                float val = acc[i][j][r];
                if constexpr (MODE == 0) {
                    val += e0[n];   // qkv bias, o = n in [0,1024)
                    if (n < 512) ob0[((size_t)z * NN + m) * NC + n] = f2bf(val * ATTN_SCALE);
                    else         ob1[((size_t)z * NN + m) * NC + (n - 512)] = f2bf(val);
                } else if constexpr (MODE == 1) {
                    val += e0[1024 + m];   // v bias, channel = m
                    ob0[((size_t)z * NC + m) * NN + n] = f2bf(val);
                } else {   // MODE 4
                    size_t idx = ((size_t)z * NC + m) * NN + n;
                    outf[idx] = val + e0[m] + e1[idx];
                }
            }
        }
    }
}

// ---------------------------------------------------------------------------
// QK^T GEMM (dedicated): SP = exp(qt·kt^T), row-sums into Lsum.
// Round-4: BK=64 -> each operand row fetched as a FULL 128B line per stage
// (r2/r3 BK=32 fetched 64B half-lines; 1.86 TB/s plateau unexplained by
// conflicts/occupancy/latency-depth -> granularity is the untested knob).
// NBUF=2 (64KB LDS, 2 blk/CU -- r2 showed occupancy 29->40% changed nothing).
// Swizzle for 128B row stride: slot' = slot ^ (row&7) (16 frag lanes -> 8
// slots x 2 = 2-way = free). XCD decode kept from r3: each XCD owns 16
// m-tiles of one batch (qt panels 2MB L2-resident), n-tile slow.
// ---------------------------------------------------------------------------
__global__ __launch_bounds__(256, 2) void qk_gemm(
    const unsigned short* __restrict__ qt,
    const unsigned short* __restrict__ kt,
    float* __restrict__ Lsum,
    unsigned short* __restrict__ SP)
{
    const int id = blockIdx.x;
    const int xcd = id & 7, j = id >> 3;      // j in [0,512)
    const int row = xcd * 16 + (j & 15);      // [0,128)
    const int z = row >> 5;
    const int m0 = (row & 31) * 128;
    const int n0 = (j >> 4) * 128;

    const size_t bnc = (size_t)NN * NC, bss = (size_t)NN * NN;
    const unsigned short* A = qt + (size_t)z * bnc;
    const unsigned short* B = kt + (size_t)z * bnc;

    __shared__ __attribute__((aligned(16))) unsigned short As[2][128 * 64];  // 32 KB
    __shared__ __attribute__((aligned(16))) unsigned short Bs[2][128 * 64];  // 32 KB

    const int t = threadIdx.x, lane = t & 63, w = t >> 6;
    const int wr = w >> 1, wc = w & 1;

    // staging: one round = 256 thr x 16B = 32 rows x 128B (full lines).
    const int sra = t >> 3;                        // 0..31
    const int scs = ((t & 7) ^ (sra & 7)) * 8;     // pre-swizzled col (elems)
    const int sdst = t * 8;                        // linear dest within round

    floatx4 acc[4][4] = {};

    auto stage = [&](int buf, int k0) {
#pragma unroll
        for (int s = 0; s < 4; ++s)
            gload_lds16(A + (size_t)(m0 + s * 32 + sra) * 512 + k0 + scs,
                        &As[buf][s * 2048 + sdst]);
#pragma unroll
        for (int s = 0; s < 4; ++s)
            gload_lds16(B + (size_t)(n0 + s * 32 + sra) * 512 + k0 + scs,
                        &Bs[buf][s * 2048 + sdst]);
    };

    auto compute = [&](int buf) {
#pragma unroll
        for (int kk = 0; kk < 2; ++kk) {
            bf16x8 af[4], bfr[4];
#pragma unroll
            for (int i = 0; i < 4; ++i) {
                const int ra = wr * 64 + i * 16 + (lane & 15);
                af[i] = *(const bf16x8*)(&As[buf][ra * 64 +
                        (((kk * 4 + (lane >> 4)) ^ (ra & 7)) * 8)]);
            }
#pragma unroll
            for (int jf = 0; jf < 4; ++jf) {
                const int rb = wc * 64 + jf * 16 + (lane & 15);
                bfr[jf] = *(const bf16x8*)(&Bs[buf][rb * 64 +
                        (((kk * 4 + (lane >> 4)) ^ (rb & 7)) * 8)]);
            }
#pragma unroll
            for (int i = 0; i < 4; ++i)
#pragma unroll
                for (int jf = 0; jf < 4; ++jf)
                    acc[i][jf] = __builtin_amdgcn_mfma_f32_16x16x32_bf16(
                        af[i], bfr[jf], acc[i][jf], 0, 0, 0);
        }
    };

    stage(0, 0);
    asm volatile("s_waitcnt vmcnt(0)" ::: "memory");
    __builtin_amdgcn_s_barrier();
#pragma unroll
    for (int kt = 0; kt < 7; ++kt) {
        stage((kt + 1) & 1, (kt + 1) * 64);   // prefetch next K-tile
        compute(kt & 1);
        asm volatile("s_waitcnt lgkmcnt(0)" ::: "memory");
        asm volatile("s_waitcnt vmcnt(0)" ::: "memory");
        __builtin_amdgcn_s_barrier();
    }
    compute(1);

    // Epilogue: exp + truncated bf16 store + per-row sum
    const int fr = lane >> 4;
    const int fc = lane & 15;
    float rs[4][4];
#pragma unroll
    for (int i = 0; i < 4; ++i)
#pragma unroll
        for (int r = 0; r < 4; ++r) rs[i][r] = 0.f;
#pragma unroll
    for (int i = 0; i < 4; ++i) {
#pragma unroll
        for (int jf = 0; jf < 4; ++jf) {
            int n = n0 + wc * 64 + jf * 16 + fc;
            int mbase = m0 + wr * 64 + i * 16 + fr * 4;
#pragma unroll
            for (int r = 0; r < 4; ++r) {
                float e = __expf(acc[i][jf][r]);
                SP[(size_t)z * bss + (size_t)(mbase + r) * NN + n] = f2bf_trunc(e);
                rs[i][r] += e;
            }
        }
    }
#pragma unroll
    for (int i = 0; i < 4; ++i) {
#pragma unroll
        for (int r = 0; r < 4; ++r) {
            float v = rs[i][r];
            v += __shfl_xor(v, 1, 16);
            v += __shfl_xor(v, 2, 16);
            v += __shfl_xor(v, 4, 16);
            v += __shfl_xor(v, 8, 16);
            if (fc == 0) {
                int m = m0 + wr * 64 + i * 16 + fr * 4 + r;
                atomicAdd(&Lsum[z * NN + m], v);
            }
        }
    }
}

// ---------------------------------------------------------------------------
// PV GEMM: O[p,c] = (sum_m P[p,m] * V[m,c]) / L[p]   (round-1 proven version)
// BM=64 x BN=128, BK=64, 1024 blocks = 4 blocks/CU, XOR-swizzled LDS,
// XCD-aware 1-D block decode.
// ---------------------------------------------------------------------------
__global__ __launch_bounds__(256, 4) void pv_gemm(
    const unsigned short* __restrict__ Abase,
    const unsigned short* __restrict__ Bbase,
    const float* __restrict__ L,
    unsigned short* __restrict__ Ob)
{
    // id -> (xcd, j); same-XCD ids are spaced 8 apart. c cycles fastest.
    const int id = blockIdx.x;
    const int xcd = id & 7;
    const int j0 = id >> 3;
    const int ct = j0 & 3;          // c-tile 0..3
    const int pairl = j0 >> 2;      // 0..31 per XCD
    const int p = pairl * 8 + xcd;  // 0..255 bijective
    const int ptile = p & 63, z = p >> 6;

    const size_t bss = (size_t)NN * NN, bnc = (size_t)NN * NC;
    const unsigned short* A = Abase + (size_t)z * bss;   // SP: (p, m)
    const unsigned short* B = Bbase + (size_t)z * bnc;   // V^T: (c, m)
    const int m0 = ptile * 64;
    const int n0 = ct * 128;

    __shared__ __attribute__((aligned(16))) unsigned short As[64 * 64];    // 8 KB
    __shared__ __attribute__((aligned(16))) unsigned short Bs[128 * 64];   // 16 KB

    const int t = threadIdx.x;
    const int lane = t & 63;
    const int w = t >> 6;
    const int wr = w >> 1, wc = w & 1;

    // staging: one gload round = 256 threads x 16B = 32 rows x 64 cols.
    const int sr = w * 8 + (lane >> 3);
    const int scs = ((lane & 7) ^ (lane >> 3)) * 8;   // pre-swizzled col (elems)
    const int lds_elem = w * 512;

    floatx4 acc[2][4] = {};

    for (int k0 = 0; k0 < NN; k0 += 64) {
#pragma unroll
        for (int s = 0; s < 2; ++s)
            gload_lds16(A + (size_t)(m0 + s * 32 + sr) * NN + k0 + scs,
                        As + s * 2048 + lds_elem);
#pragma unroll
        for (int s = 0; s < 4; ++s)
            gload_lds16(B + (size_t)(n0 + s * 32 + sr) * NN + k0 + scs,
                        Bs + s * 2048 + lds_elem);
        __syncthreads();

        bf16x8 af[2][2], bfr[4][2];
#pragma unroll
        for (int i = 0; i < 2; ++i) {
            const int ra = wr * 32 + i * 16 + (lane & 15);
#pragma unroll
            for (int kk = 0; kk < 2; ++kk)
                af[i][kk] = *(const bf16x8*)(As + ra * 64 +
                    (((kk * 4 + (lane >> 4)) ^ (ra & 7)) * 8));
        }
#pragma unroll
        for (int jj = 0; jj < 4; ++jj) {
            const int rb = wc * 64 + jj * 16 + (lane & 15);
#pragma unroll
            for (int kk = 0; kk < 2; ++kk)
                bfr[jj][kk] = *(const bf16x8*)(Bs + rb * 64 +
                    (((kk * 4 + (lane >> 4)) ^ (rb & 7)) * 8));
        }
#pragma unroll
        for (int kk = 0; kk < 2; ++kk)
#pragma unroll
            for (int i = 0; i < 2; ++i)
#pragma unroll
                for (int jj = 0; jj < 4; ++jj)
                    acc[i][jj] = __builtin_amdgcn_mfma_f32_16x16x32_bf16(
                        af[i][kk], bfr[jj][kk], acc[i][jj], 0, 0, 0);
        __syncthreads();
    }

    const int fr = lane >> 4;
    const int fc = lane & 15;
#pragma unroll
    for (int i = 0; i < 2; ++i) {
#pragma unroll
        for (int r = 0; r < 4; ++r) {
            int m = m0 + wr * 32 + i * 16 + fr * 4 + r;
            float linv = 1.0f / L[z * NN + m];
#pragma unroll
            for (int jj = 0; jj < 4; ++jj) {
                int n = n0 + wc * 64 + jj * 16 + fc;
                Ob[(size_t)z * bnc + (size_t)m * NC + n] = f2bf(acc[i][jj][r] * linv);
            }
        }
    }
}

// ---------------------------------------------------------------------------
extern "C" void kernel_launch(void* const* d_in, const int* in_sizes, int n_in,
                              void* d_out, int out_size, void* d_ws, size_t ws_size,
                              hipStream_t stream)
{
    const float* x     = (const float*)d_in[0];
    const float* gn_w  = (const float*)d_in[1];
    const float* gn_b  = (const float*)d_in[2];
    const float* qkv_w = (const float*)d_in[3];
    const float* qkv_b = (const float*)d_in[4];
    const float* out_w = (const float*)d_in[5];
    const float* out_b = (const float*)d_in[6];
    float* out = (float*)d_out;

    const size_t bnc = (size_t)NN * NC;          // 2,097,152 per batch
    char* w = (char*)d_ws;
    float* ss   = (float*)w;                 w += 16384;
    float* part = (float*)w;                 w += 8192;
    float* Lsum = (float*)w;                 w += (size_t)NB * NN * 4;  // row sums
    unsigned short* wq = (unsigned short*)w; w += (size_t)1536 * 512 * 2;
    unsigned short* wo = (unsigned short*)w; w += (size_t)512 * 512 * 2;
    unsigned short* qt = (unsigned short*)w; w += NB * bnc * 2;   // (b,n,c) pre-scaled
    unsigned short* kt = (unsigned short*)w; w += NB * bnc * 2;   // (b,n,c)
    unsigned short* vt = (unsigned short*)w; w += NB * bnc * 2;   // (b,c,n)
    unsigned short* SP = (unsigned short*)w; w += (size_t)NB * NN * NN * 2; // 128 MB
    // Aliases (lifetime-disjoint):
    unsigned short* ht = SP;   // ht (b,n,c) dead before qk_gemm writes SP
    unsigned short* Ob = qt;   // Ob (b,n,c) written after qt last read (qk_gemm)

    hipMemsetAsync(Lsum, 0, (size_t)NB * NN * sizeof(float), stream);

    gn_partial_kernel<<<1024, 256, 0, stream>>>(x, part);
    gn_final_kernel<<<1, 128, 0, stream>>>(part, gn_w, gn_b, ss);
    wconv_kernel<<<(1536 * 512 + 512 * 512) / 256, 256, 0, stream>>>(qkv_w, out_w, wq, wo);
    htnorm_kernel<<<dim3(NN / 32, NC / 32, NB), 256, 0, stream>>>(x, ss, ht);

    // q/k: C[p,o] = ht · wqk^T   (q pre-scaled by ATTN_SCALE)
    mfma_gemm<0, 128, 128, 512, 3, 3><<<dim3(1024 / 128, NN / 128, NB), 256, 0, stream>>>(
        ht, wq, qkv_b, nullptr, nullptr, qt, kt);
    // v: C[c,p] = wv · ht^T   (64x128 tile -> 1024 blocks = 4/CU)
    mfma_gemm<1, 64, 128, 512, 3, 4><<<dim3(NN / 128, 512 / 64, NB), 256, 0, stream>>>(
        wq + (size_t)1024 * 512, ht, qkv_b, nullptr, nullptr, vt, nullptr);

    // QK^T + exp + row-sum accumulation; 1-D grid, XCD-decoded inside
    qk_gemm<<<dim3(4096), 256, 0, stream>>>(qt, kt, Lsum, SP);
    // PV + normalize, all batches, 1024 blocks (XCD-decoded inside)
    pv_gemm<<<dim3(1024), 256, 0, stream>>>(SP, vt, Lsum, Ob);

    // out projection + bias + residual (64x128 tile -> 1024 blocks = 4/CU)
    mfma_gemm<4, 64, 128, 512, 3, 4><<<dim3(NN / 128, 512 / 64, NB), 256, 0, stream>>>(
        wo, Ob, out_b, x, out, nullptr, nullptr);
}

// Round 5
// 356.151 us; speedup vs baseline: 1.1739x; 1.0371x over previous
//
#include <hip/hip_runtime.h>
#include <cmath>

// b=4, c=512, h=w=64 -> n=4096, groups=32 (16 ch/group)
#define NB 4
#define NC 512
#define NN 4096
#define ATTN_SCALE 0.04419417382415922f  // 512^-0.5

typedef __bf16 bf16x8 __attribute__((ext_vector_type(8)));
typedef float floatx4 __attribute__((ext_vector_type(4)));

__device__ __forceinline__ unsigned short f2bf(float f) {
    union { float f; unsigned int u; } v; v.f = f;
    return (unsigned short)((v.u + 0x7fffu + ((v.u >> 16) & 1u)) >> 16);
}
__device__ __forceinline__ unsigned short f2bf_trunc(float f) {
    union { float f; unsigned int u; } v; v.f = f;
    return (unsigned short)(v.u >> 16);
}

__device__ __forceinline__ void gload_lds16(const unsigned short* gp, unsigned short* lp) {
    __builtin_amdgcn_global_load_lds(
        (const __attribute__((address_space(1))) void*)gp,
        (__attribute__((address_space(3))) void*)lp, 16, 0, 0);
}

template<int N> __device__ __forceinline__ void wait_vmcnt() {
    if constexpr (N == 0) asm volatile("s_waitcnt vmcnt(0)" ::: "memory");
    else if constexpr (N == 3) asm volatile("s_waitcnt vmcnt(3)" ::: "memory");
    else if constexpr (N == 4) asm volatile("s_waitcnt vmcnt(4)" ::: "memory");
    else if constexpr (N == 6) asm volatile("s_waitcnt vmcnt(6)" ::: "memory");
}

// ---------------------------------------------------------------------------
// Kernel 1a: GroupNorm partial sums. 1024 blocks = (b,g) x 8 slices.
// ---------------------------------------------------------------------------
__global__ __launch_bounds__(256) void gn_partial_kernel(
    const float* __restrict__ x, float* __restrict__ part)
{
    int blk = blockIdx.x;
    int bg = blk >> 3, sub = blk & 7;
    const float4* xv = (const float4*)(x + (size_t)bg * 16 * NN + (size_t)sub * 8192);
    float s1 = 0.f, s2 = 0.f;
#pragma unroll
    for (int i = 0; i < 8; ++i) {
        float4 v = xv[threadIdx.x + i * 256];
        s1 += v.x + v.y + v.z + v.w;
        s2 += v.x * v.x + v.y * v.y + v.z * v.z + v.w * v.w;
    }
#pragma unroll
    for (int off = 32; off; off >>= 1) {
        s1 += __shfl_xor(s1, off, 64);
        s2 += __shfl_xor(s2, off, 64);
    }
    __shared__ float r1[4], r2[4];
    int lane = threadIdx.x & 63, w = threadIdx.x >> 6;
    if (lane == 0) { r1[w] = s1; r2[w] = s2; }
    __syncthreads();
    if (threadIdx.x == 0) {
        part[blk * 2]     = r1[0] + r1[1] + r1[2] + r1[3];
        part[blk * 2 + 1] = r2[0] + r2[1] + r2[2] + r2[3];
    }
}

// Kernel 1b: finalize -> per-channel scale/shift
__global__ __launch_bounds__(128) void gn_final_kernel(
    const float* __restrict__ part, const float* __restrict__ gw,
    const float* __restrict__ gb, float* __restrict__ ss)
{
    int tg = threadIdx.x;            // 0..127 = b*32+g
    int b = tg >> 5, g = tg & 31;
    float s1 = 0.f, s2 = 0.f;
#pragma unroll
    for (int s = 0; s < 8; ++s) {
        s1 += part[(tg * 8 + s) * 2];
        s2 += part[(tg * 8 + s) * 2 + 1];
    }
    float mean = s1 * (1.0f / 65536.0f);
    float var  = s2 * (1.0f / 65536.0f) - mean * mean;
    float rstd = rsqrtf(var + 1e-5f);
#pragma unroll
    for (int i = 0; i < 16; ++i) {
        int c = g * 16 + i;
        float sc = rstd * gw[c];
        ss[b * NC + c] = sc;
        ss[2048 + b * NC + c] = gb[c] - mean * sc;
    }
}

// ---------------------------------------------------------------------------
// Kernel 2: convert weights fp32 -> bf16
// ---------------------------------------------------------------------------
__global__ __launch_bounds__(256) void wconv_kernel(
    const float* __restrict__ qkv_w, const float* __restrict__ out_w,
    unsigned short* __restrict__ wq, unsigned short* __restrict__ wo)
{
    int i = blockIdx.x * 256 + threadIdx.x;
    const int NQ = 1536 * 512;
    if (i < NQ) wq[i] = f2bf(qkv_w[i]);
    else        wo[i - NQ] = f2bf(out_w[i - NQ]);
}

// ---------------------------------------------------------------------------
// Kernel 3: normalize + transpose: x (b,c,n) fp32 -> h_t (b,n,c) bf16
// ---------------------------------------------------------------------------
__global__ __launch_bounds__(256) void htnorm_kernel(
    const float* __restrict__ x, const float* __restrict__ ss,
    unsigned short* __restrict__ ht)
{
    int b = blockIdx.z;
    int c0 = blockIdx.y * 32, n0 = blockIdx.x * 32;
    __shared__ float T[32][33];
    int tx = threadIdx.x & 31, ty = threadIdx.x >> 5;   // ty 0..7
    const float* xb = x + ((size_t)b * NC + c0) * NN;
    const float* sc = ss + b * NC + c0;
    const float* sh = ss + 2048 + b * NC + c0;
#pragma unroll
    for (int i = 0; i < 4; ++i) {
        int c = ty + i * 8;
        T[c][tx] = xb[(size_t)c * NN + n0 + tx] * sc[c] + sh[c];
    }
    __syncthreads();
    unsigned short* hb = ht + ((size_t)b * NN + n0) * NC + c0;
#pragma unroll
    for (int i = 0; i < 4; ++i) {
        int n = ty + i * 8;
        hb[(size_t)n * NC + tx] = f2bf(T[tx][n]);
    }
}

// ---------------------------------------------------------------------------
// MFMA NT GEMM: C[m,n] = sum_k A[m,k]*B[n,k], BK=32, KD=512.
// Counted-vmcnt multi-buffer pipeline (NBUF=3, DEPTH=2, vmcnt never 0 in loop).
// Round-5: qk (MODE 2) enlarged to BM=256 (wave tile 128x64, FI=8): the
// phase-sum model (LDS 41 + HBM 37 + MFMA 28 + VALU 23 us ~= 123 measured)
// says the LDS-pipe addend is the biggest reducible term; 12 ds_read_b128
// now feed 32 MFMA (was 8:16) and grid halves -> reads/output x0.67.
// MODE 0: qkv q/k   M=4096 N=1024 K=512  A=ht(+z) B=wqk    -> qt(*scale)/kt +bias
// MODE 1: qkv v     M=512  N=4096 K=512  A=wv     B=ht(+z) -> vt (c,p) bf16 +bias
// MODE 2: QK^T      M=4096 N=4096 K=512  A=qt(+z) B=kt(+z) -> SP = exp(s) bf16,
//                   row-sums atomically accumulated into outf = L[b*NN+row]
// MODE 4: out proj  M=512  N=4096 K=512  A=wo     B=Ob(+z) -> out fp32 +bias+res
// ---------------------------------------------------------------------------
template<int MODE, int BM, int BN, int KD, int NBUF, int MINB>
__global__ __launch_bounds__(256, MINB) void mfma_gemm(
    const unsigned short* __restrict__ Abase,
    const unsigned short* __restrict__ Bbase,
    const float* __restrict__ e0, const float* __restrict__ e1,
    float* __restrict__ outf,
    unsigned short* __restrict__ ob0, unsigned short* __restrict__ ob1)
{
    constexpr int NT = KD / 32;
    constexpr int FI = BM / 32;       // frag rows per wave
    constexpr int FJ = BN / 32;       // frag cols per wave
    constexpr int LPS = BM / 64 + BN / 64;   // gloads per thread per stage
    constexpr int DEPTH = NBUF - 1;
    const size_t bnc = (size_t)NN * NC;
    const size_t bss = (size_t)NN * NN;

    int z, m0, n0;
    if constexpr (MODE == 2) {
        // XCD-grouped 1-D decode (grid 2048, rr dispatch): each XCD owns 8
        // m-tiles (2MB qt panel L2-resident), n-tile slow.
        const int id = blockIdx.x;
        const int xcd = id & 7, j = id >> 3;       // j in [0,256)
        const int mi = xcd * 8 + (j & 7);          // [0,64)
        z = mi >> 4; m0 = (mi & 15) * BM; n0 = (j >> 3) * BN;
    } else {
        z = blockIdx.z; m0 = blockIdx.y * BM; n0 = blockIdx.x * BN;
    }

    const unsigned short* A;
    const unsigned short* B;
    if constexpr (MODE == 0)      { A = Abase + (size_t)z * bnc; B = Bbase; }
    else if constexpr (MODE == 1) { A = Abase; B = Bbase + (size_t)z * bnc; }
    else if constexpr (MODE == 2) { A = Abase + (size_t)z * bnc; B = Bbase + (size_t)z * bnc; }
    else                          { A = Abase; B = Bbase + (size_t)z * bnc; }

    __shared__ __attribute__((aligned(16))) unsigned short As[NBUF][BM * 32];
    __shared__ __attribute__((aligned(16))) unsigned short Bs[NBUF][BN * 32];

    const int t = threadIdx.x;
    const int lane = t & 63;
    const int w = t >> 6;
    const int wr = w >> 1, wc = w & 1;

    // staging: one gload round = 256 threads x 16B = 64 rows x 32 cols.
    const int sr = w * 16 + (lane >> 2);                    // row in 64-row slab
    const int scs = ((lane & 3) ^ ((lane >> 3) & 3)) * 8;   // pre-swizzled col
    const int lds_elem = w * 512;
    const int kslot = lane >> 4;

    floatx4 acc[FI][FJ] = {};

    auto stage = [&](int buf, int tile) {
        const int k0 = tile * 32;
#pragma unroll
        for (int s = 0; s < BM / 64; ++s)
            gload_lds16(A + (size_t)(m0 + s * 64 + sr) * KD + k0 + scs,
                        &As[buf][s * 2048 + lds_elem]);
#pragma unroll
        for (int s = 0; s < BN / 64; ++s)
            gload_lds16(B + (size_t)(n0 + s * 64 + sr) * KD + k0 + scs,
                        &Bs[buf][s * 2048 + lds_elem]);
    };

    auto compute = [&](int buf) {
        bf16x8 af[FI], bfr[FJ];
#pragma unroll
        for (int i = 0; i < FI; ++i) {
            const int ra = wr * (BM / 2) + i * 16 + (lane & 15);
            af[i] = *(const bf16x8*)(&As[buf][ra * 32 + ((kslot ^ ((ra >> 1) & 3)) * 8)]);
        }
#pragma unroll
        for (int j = 0; j < FJ; ++j) {
            const int rb = wc * (BN / 2) + j * 16 + (lane & 15);
            bfr[j] = *(const bf16x8*)(&Bs[buf][rb * 32 + ((kslot ^ ((rb >> 1) & 3)) * 8)]);
        }
#pragma unroll
        for (int i = 0; i < FI; ++i)
#pragma unroll
            for (int j = 0; j < FJ; ++j)
                acc[i][j] = __builtin_amdgcn_mfma_f32_16x16x32_bf16(
                    af[i], bfr[j], acc[i][j], 0, 0, 0);
    };

    // ---- prologue: fill DEPTH tiles, wait for tile 0 only ----
#pragma unroll
    for (int d = 0; d < DEPTH; ++d) stage(d, d);
    wait_vmcnt<(DEPTH - 1) * LPS>();
    __builtin_amdgcn_s_barrier();

#pragma unroll
    for (int kt = 0; kt < NT - DEPTH; ++kt) {
        stage((kt + DEPTH) % NBUF, kt + DEPTH);
        compute(kt % NBUF);
        asm volatile("s_waitcnt lgkmcnt(0)" ::: "memory");
        wait_vmcnt<(DEPTH - 1) * LPS>();
        __builtin_amdgcn_s_barrier();
    }

    // ---- tail: drain remaining DEPTH(=2) tiles ----
    compute((NT - 2) % NBUF);
    asm volatile("s_waitcnt lgkmcnt(0)" ::: "memory");
    wait_vmcnt<0>();
    __builtin_amdgcn_s_barrier();
    compute((NT - 1) % NBUF);

    // ---- Epilogue. C/D: col = lane&15, row = (lane>>4)*4 + reg ----
    const int fr = lane >> 4;
    const int fc = lane & 15;

    if constexpr (MODE == 2) {
        // exp + truncated bf16 store + per-row sum (16-lane reduce + atomicAdd)
        float rs[FI][4];
#pragma unroll
        for (int i = 0; i < FI; ++i)
#pragma unroll
            for (int r = 0; r < 4; ++r) rs[i][r] = 0.f;
#pragma unroll
        for (int i = 0; i < FI; ++i) {
#pragma unroll
            for (int j = 0; j < FJ; ++j) {
                int n = n0 + wc * (BN / 2) + j * 16 + fc;
                int mbase = m0 + wr * (BM / 2) + i * 16 + fr * 4;
#pragma unroll
                for (int r = 0; r < 4; ++r) {
                    float e = __expf(acc[i][j][r]);
                    ob0[(size_t)z * bss + (size_t)(mbase + r) * NN + n] = f2bf_trunc(e);
                    rs[i][r] += e;
                }
            }
        }
#pragma unroll
        for (int i = 0; i < FI; ++i) {
#pragma unroll
            for (int r = 0; r < 4; ++r) {
                float v = rs[i][r];
                v += __shfl_xor(v, 1, 16);
                v += __shfl_xor(v, 2, 16);
                v += __shfl_xor(v, 4, 16);
                v += __shfl_xor(v, 8, 16);
                if (fc == 0) {
                    int m = m0 + wr * (BM / 2) + i * 16 + fr * 4 + r;
                    atomicAdd(&outf[z * NN + m], v);
                }
            }
        }
        return;
    }

#pragma unroll
    for (int i = 0; i < FI; ++i) {
#pragma unroll
        for (int j = 0; j < FJ; ++j) {
            int n = n0 + wc * (BN / 2) + j * 16 + fc;
            int mbase = m0 + wr * (BM / 2) + i * 16 + fr * 4;
#pragma unroll
            for (int r = 0; r < 4; ++r) {
                int m = mbase + r;
                float val = acc[i][j][r];
                if constexpr (MODE == 0) {
                    val += e0[n];   // qkv bias, o = n in [0,1024)
                    if (n < 512) ob0[((size_t)z * NN + m) * NC + n] = f2bf(val * ATTN_SCALE);
                    else         ob1[((size_t)z * NN + m) * NC + (n - 512)] = f2bf(val);
                } else if constexpr (MODE == 1) {
                    val += e0[1024 + m];   // v bias, channel = m
                    ob0[((size_t)z * NC + m) * NN + n] = f2bf(val);
                } else {   // MODE 4
                    size_t idx = ((size_t)z * NC + m) * NN + n;
                    outf[idx] = val + e0[m] + e1[idx];
                }
            }
        }
    }
}

// ---------------------------------------------------------------------------
// PV GEMM: O[p,c] = (sum_m P[p,m] * V[m,c]) / L[p]
// Round-5: BM=128 x BN=128 (wave tile 64x64, FI=4): LDS reads/MFMA 0.75->0.5.
// BK=64 kept (full 128B SP-row lines; BK=32 regressed in r3). Double-buffered
// prefetch, 64 KB LDS -> 2 blk/CU, grid 512, XCD-aware decode (4 c-tile
// siblings of each (z,ptile) consecutive on one XCD -> SP panel L2-shared).
// ---------------------------------------------------------------------------
__global__ __launch_bounds__(256, 2) void pv_gemm(
    const unsigned short* __restrict__ Abase,
    const unsigned short* __restrict__ Bbase,
    const float* __restrict__ L,
    unsigned short* __restrict__ Ob)
{
    const int id = blockIdx.x;
    const int xcd = id & 7;
    const int j0 = id >> 3;          // [0,64)
    const int ct = j0 & 3;           // c-tile 0..3 (fastest -> same XCD)
    const int p = (j0 >> 2) * 8 + xcd;   // [0,128) bijective
    const int ptile = p & 31, z = p >> 5;

    const size_t bss = (size_t)NN * NN, bnc = (size_t)NN * NC;
    const unsigned short* A = Abase + (size_t)z * bss;   // SP: (p, m)
    const unsigned short* B = Bbase + (size_t)z * bnc;   // V^T: (c, m)
    const int m0 = ptile * 128;
    const int n0 = ct * 128;

    __shared__ __attribute__((aligned(16))) unsigned short As[2][128 * 64];  // 32 KB
    __shared__ __attribute__((aligned(16))) unsigned short Bs[2][128 * 64];  // 32 KB

    const int t = threadIdx.x;
    const int lane = t & 63;
    const int w = t >> 6;
    const int wr = w >> 1, wc = w & 1;

    // staging: one gload round = 256 threads x 16B = 32 rows x 64 cols.
    // row&7 == lane>>3 (wave-invariant pre-swizzled source slot).
    const int sr = w * 8 + (lane >> 3);
    const int scs = ((lane & 7) ^ (lane >> 3)) * 8;   // pre-swizzled col (elems)
    const int lds_elem = w * 512;

    floatx4 acc[4][4] = {};

    auto stage = [&](int buf, int k0) {
#pragma unroll
        for (int s = 0; s < 4; ++s)
            gload_lds16(A + (size_t)(m0 + s * 32 + sr) * NN + k0 + scs,
                        &As[buf][s * 2048 + lds_elem]);
#pragma unroll
        for (int s = 0; s < 4; ++s)
            gload_lds16(B + (size_t)(n0 + s * 32 + sr) * NN + k0 + scs,
                        &Bs[buf][s * 2048 + lds_elem]);
    };

    auto compute = [&](int buf) {
#pragma unroll
        for (int kk = 0; kk < 2; ++kk) {
            bf16x8 af[4], bfr[4];
#pragma unroll
            for (int i = 0; i < 4; ++i) {
                const int ra = wr * 64 + i * 16 + (lane & 15);
                af[i] = *(const bf16x8*)(&As[buf][ra * 64 +
                        (((kk * 4 + (lane >> 4)) ^ (ra & 7)) * 8)]);
            }
#pragma unroll
            for (int jf = 0; jf < 4; ++jf) {
                const int rb = wc * 64 + jf * 16 + (lane & 15);
                bfr[jf] = *(const bf16x8*)(&Bs[buf][rb * 64 +
                        (((kk * 4 + (lane >> 4)) ^ (rb & 7)) * 8)]);
            }
#pragma unroll
            for (int i = 0; i < 4; ++i)
#pragma unroll
                for (int jf = 0; jf < 4; ++jf)
                    acc[i][jf] = __builtin_amdgcn_mfma_f32_16x16x32_bf16(
                        af[i], bfr[jf], acc[i][jf], 0, 0, 0);
        }
    };

    stage(0, 0);
    asm volatile("s_waitcnt vmcnt(0)" ::: "memory");
    __builtin_amdgcn_s_barrier();
    for (int kc = 0; kc < 63; ++kc) {
        stage((kc + 1) & 1, (kc + 1) * 64);   // prefetch next chunk (async)
        compute(kc & 1);
        asm volatile("s_waitcnt lgkmcnt(0)" ::: "memory");
        asm volatile("s_waitcnt vmcnt(0)" ::: "memory");
        __builtin_amdgcn_s_barrier();
    }
    compute(1);

    const int fr = lane >> 4;
    const int fc = lane & 15;
#pragma unroll
    for (int i = 0; i < 4; ++i) {
#pragma unroll
        for (int r = 0; r < 4; ++r) {
            int m = m0 + wr * 64 + i * 16 + fr * 4 + r;
            float linv = 1.0f / L[z * NN + m];
#pragma unroll
            for (int jf = 0; jf < 4; ++jf) {
                int n = n0 + wc * 64 + jf * 16 + fc;
                Ob[(size_t)z * bnc + (size_t)m * NC + n] = f2bf(acc[i][jf][r] * linv);
            }
        }
    }
}

// ---------------------------------------------------------------------------
extern "C" void kernel_launch(void* const* d_in, const int* in_sizes, int n_in,
                              void* d_out, int out_size, void* d_ws, size_t ws_size,
                              hipStream_t stream)
{
    const float* x     = (const float*)d_in[0];
    const float* gn_w  = (const float*)d_in[1];
    const float* gn_b  = (const float*)d_in[2];
    const float* qkv_w = (const float*)d_in[3];
    const float* qkv_b = (const float*)d_in[4];
    const float* out_w = (const float*)d_in[5];
    const float* out_b = (const float*)d_in[6];
    float* out = (float*)d_out;

    const size_t bnc = (size_t)NN * NC;          // 2,097,152 per batch
    char* w = (char*)d_ws;
    float* ss   = (float*)w;                 w += 16384;
    float* part = (float*)w;                 w += 8192;
    float* Lsum = (float*)w;                 w += (size_t)NB * NN * 4;  // row sums
    unsigned short* wq = (unsigned short*)w; w += (size_t)1536 * 512 * 2;
    unsigned short* wo = (unsigned short*)w; w += (size_t)512 * 512 * 2;
    unsigned short* qt = (unsigned short*)w; w += NB * bnc * 2;   // (b,n,c) pre-scaled
    unsigned short* kt = (unsigned short*)w; w += NB * bnc * 2;   // (b,n,c)
    unsigned short* vt = (unsigned short*)w; w += NB * bnc * 2;   // (b,c,n)
    unsigned short* SP = (unsigned short*)w; w += (size_t)NB * NN * NN * 2; // 128 MB
    // Aliases (lifetime-disjoint):
    unsigned short* ht = SP;   // ht (b,n,c) dead before MODE 2 writes SP
    unsigned short* Ob = qt;   // Ob (b,n,c) written after qt last read (MODE 2)

    hipMemsetAsync(Lsum, 0, (size_t)NB * NN * sizeof(float), stream);

    gn_partial_kernel<<<1024, 256, 0, stream>>>(x, part);
    gn_final_kernel<<<1, 128, 0, stream>>>(part, gn_w, gn_b, ss);
    wconv_kernel<<<(1536 * 512 + 512 * 512) / 256, 256, 0, stream>>>(qkv_w, out_w, wq, wo);
    htnorm_kernel<<<dim3(NN / 32, NC / 32, NB), 256, 0, stream>>>(x, ss, ht);

    // q/k: C[p,o] = ht · wqk^T   (q pre-scaled by ATTN_SCALE)
    mfma_gemm<0, 128, 128, 512, 3, 3><<<dim3(1024 / 128, NN / 128, NB), 256, 0, stream>>>(
        ht, wq, qkv_b, nullptr, nullptr, qt, kt);
    // v: C[c,p] = wv · ht^T   (64x128 tile -> 1024 blocks = 4/CU)
    mfma_gemm<1, 64, 128, 512, 3, 4><<<dim3(NN / 128, 512 / 64, NB), 256, 0, stream>>>(
        wq + (size_t)1024 * 512, ht, qkv_b, nullptr, nullptr, vt, nullptr);

    // QK^T + exp + row-sum; BM=256 wave-tile 128x64, 2048 blocks, XCD-decoded
    mfma_gemm<2, 256, 128, 512, 3, 2><<<dim3(2048), 256, 0, stream>>>(
        qt, kt, nullptr, nullptr, Lsum, SP, nullptr);
    // PV + normalize; BM=128xBN=128 wave-tile 64x64, 512 blocks, XCD-decoded
    pv_gemm<<<dim3(512), 256, 0, stream>>>(SP, vt, Lsum, Ob);

    // out projection + bias + residual (64x128 tile -> 1024 blocks = 4/CU)
    mfma_gemm<4, 64, 128, 512, 3, 4><<<dim3(NN / 128, 512 / 64, NB), 256, 0, stream>>>(
        wo, Ob, out_b, x, out, nullptr, nullptr);
}

// Round 6
// 353.044 us; speedup vs baseline: 1.1843x; 1.0088x over previous
//
#include <hip/hip_runtime.h>
#include <cmath>

// b=4, c=512, h=w=64 -> n=4096, groups=32 (16 ch/group)
#define NB 4
#define NC 512
#define NN 4096
#define ATTN_SCALE 0.04419417382415922f  // 512^-0.5

typedef __bf16 bf16x8 __attribute__((ext_vector_type(8)));
typedef float floatx4 __attribute__((ext_vector_type(4)));

__device__ __forceinline__ unsigned short f2bf(float f) {
    union { float f; unsigned int u; } v; v.f = f;
    return (unsigned short)((v.u + 0x7fffu + ((v.u >> 16) & 1u)) >> 16);
}
__device__ __forceinline__ unsigned short f2bf_trunc(float f) {
    union { float f; unsigned int u; } v; v.f = f;
    return (unsigned short)(v.u >> 16);
}

__device__ __forceinline__ void gload_lds16(const unsigned short* gp, unsigned short* lp) {
    __builtin_amdgcn_global_load_lds(
        (const __attribute__((address_space(1))) void*)gp,
        (__attribute__((address_space(3))) void*)lp, 16, 0, 0);
}

template<int N> __device__ __forceinline__ void wait_vmcnt() {
    if constexpr (N == 0) asm volatile("s_waitcnt vmcnt(0)" ::: "memory");
    else if constexpr (N == 3) asm volatile("s_waitcnt vmcnt(3)" ::: "memory");
    else if constexpr (N == 4) asm volatile("s_waitcnt vmcnt(4)" ::: "memory");
    else if constexpr (N == 6) asm volatile("s_waitcnt vmcnt(6)" ::: "memory");
}

// ---------------------------------------------------------------------------
// Kernel 1a: GroupNorm partial sums. 1024 blocks = (b,g) x 8 slices.
// ---------------------------------------------------------------------------
__global__ __launch_bounds__(256) void gn_partial_kernel(
    const float* __restrict__ x, float* __restrict__ part)
{
    int blk = blockIdx.x;
    int bg = blk >> 3, sub = blk & 7;
    const float4* xv = (const float4*)(x + (size_t)bg * 16 * NN + (size_t)sub * 8192);
    float s1 = 0.f, s2 = 0.f;
#pragma unroll
    for (int i = 0; i < 8; ++i) {
        float4 v = xv[threadIdx.x + i * 256];
        s1 += v.x + v.y + v.z + v.w;
        s2 += v.x * v.x + v.y * v.y + v.z * v.z + v.w * v.w;
    }
#pragma unroll
    for (int off = 32; off; off >>= 1) {
        s1 += __shfl_xor(s1, off, 64);
        s2 += __shfl_xor(s2, off, 64);
    }
    __shared__ float r1[4], r2[4];
    int lane = threadIdx.x & 63, w = threadIdx.x >> 6;
    if (lane == 0) { r1[w] = s1; r2[w] = s2; }
    __syncthreads();
    if (threadIdx.x == 0) {
        part[blk * 2]     = r1[0] + r1[1] + r1[2] + r1[3];
        part[blk * 2 + 1] = r2[0] + r2[1] + r2[2] + r2[3];
    }
}

// Kernel 1b: finalize -> per-channel scale/shift
__global__ __launch_bounds__(128) void gn_final_kernel(
    const float* __restrict__ part, const float* __restrict__ gw,
    const float* __restrict__ gb, float* __restrict__ ss)
{
    int tg = threadIdx.x;            // 0..127 = b*32+g
    int b = tg >> 5, g = tg & 31;
    float s1 = 0.f, s2 = 0.f;
#pragma unroll
    for (int s = 0; s < 8; ++s) {
        s1 += part[(tg * 8 + s) * 2];
        s2 += part[(tg * 8 + s) * 2 + 1];
    }
    float mean = s1 * (1.0f / 65536.0f);
    float var  = s2 * (1.0f / 65536.0f) - mean * mean;
    float rstd = rsqrtf(var + 1e-5f);
#pragma unroll
    for (int i = 0; i < 16; ++i) {
        int c = g * 16 + i;
        float sc = rstd * gw[c];
        ss[b * NC + c] = sc;
        ss[2048 + b * NC + c] = gb[c] - mean * sc;
    }
}

// ---------------------------------------------------------------------------
// Kernel 2: convert weights fp32 -> bf16
// ---------------------------------------------------------------------------
__global__ __launch_bounds__(256) void wconv_kernel(
    const float* __restrict__ qkv_w, const float* __restrict__ out_w,
    unsigned short* __restrict__ wq, unsigned short* __restrict__ wo)
{
    int i = blockIdx.x * 256 + threadIdx.x;
    const int NQ = 1536 * 512;
    if (i < NQ) wq[i] = f2bf(qkv_w[i]);
    else        wo[i - NQ] = f2bf(out_w[i - NQ]);
}

// ---------------------------------------------------------------------------
// Kernel 3: normalize + transpose: x (b,c,n) fp32 -> h_t (b,n,c) bf16
// ---------------------------------------------------------------------------
__global__ __launch_bounds__(256) void htnorm_kernel(
    const float* __restrict__ x, const float* __restrict__ ss,
    unsigned short* __restrict__ ht)
{
    int b = blockIdx.z;
    int c0 = blockIdx.y * 32, n0 = blockIdx.x * 32;
    __shared__ float T[32][33];
    int tx = threadIdx.x & 31, ty = threadIdx.x >> 5;   // ty 0..7
    const float* xb = x + ((size_t)b * NC + c0) * NN;
    const float* sc = ss + b * NC + c0;
    const float* sh = ss + 2048 + b * NC + c0;
#pragma unroll
    for (int i = 0; i < 4; ++i) {
        int c = ty + i * 8;
        T[c][tx] = xb[(size_t)c * NN + n0 + tx] * sc[c] + sh[c];
    }
    __syncthreads();
    unsigned short* hb = ht + ((size_t)b * NN + n0) * NC + c0;
#pragma unroll
    for (int i = 0; i < 4; ++i) {
        int n = ty + i * 8;
        hb[(size_t)n * NC + tx] = f2bf(T[tx][n]);
    }
}

// ---------------------------------------------------------------------------
// MFMA NT GEMM: C[m,n] = sum_k A[m,k]*B[n,k], BK=32, KD=512, NBUF=3.
// Round-6: cross-barrier LDS->reg software pipelining. r5's phase-sum model
// (LDS 31 + MFMA 33 + HBM 32 + VALU 22 ~= 109 measured) showed <10% overlap:
// barrier-lockstep waves all ds_read together then all MFMA together. With
// NBUF=3, step t+1's tile is LDS-resident during step t -> each wave reads
// step t+1's fragments into a 2nd register set WHILE step t's MFMAs run
// (independent: ds_read + MFMA co-issue on separate pipes). Ping-pong A/B
// register sets, unroll-2 (static idx, rule 20). setprio(1) around MFMA (T5:
// phase-split now exists so the CU scheduler has roles to arbitrate).
// MODE 0: qkv q/k   M=4096 N=1024 K=512  A=ht(+z) B=wqk    -> qt(*scale)/kt +bias
// MODE 1: qkv v     M=512  N=4096 K=512  A=wv     B=ht(+z) -> vt (c,p) bf16 +bias
// MODE 2: QK^T      M=4096 N=4096 K=512  A=qt(+z) B=kt(+z) -> SP = exp(s) bf16,
//                   row-sums atomically accumulated into outf = L[b*NN+row]
// MODE 4: out proj  M=512  N=4096 K=512  A=wo     B=Ob(+z) -> out fp32 +bias+res
// ---------------------------------------------------------------------------
template<int MODE, int BM, int BN, int KD, int MINB>
__global__ __launch_bounds__(256, MINB) void mfma_gemm(
    const unsigned short* __restrict__ Abase,
    const unsigned short* __restrict__ Bbase,
    const float* __restrict__ e0, const float* __restrict__ e1,
    float* __restrict__ outf,
    unsigned short* __restrict__ ob0, unsigned short* __restrict__ ob1)
{
    constexpr int NT = KD / 32;       // 16 K-steps (even)
    constexpr int FI = BM / 32;       // frag rows per wave
    constexpr int FJ = BN / 32;       // frag cols per wave
    constexpr int LPS = BM / 64 + BN / 64;   // gloads per thread per stage
    const size_t bnc = (size_t)NN * NC;
    const size_t bss = (size_t)NN * NN;

    int z, m0, n0;
    if constexpr (MODE == 2) {
        // XCD-grouped 1-D decode (grid 2048, rr dispatch): each XCD owns 8
        // m-tiles (2MB qt panel L2-resident), n-tile slow.
        const int id = blockIdx.x;
        const int xcd = id & 7, j = id >> 3;       // j in [0,256)
        const int mi = xcd * 8 + (j & 7);          // [0,64)
        z = mi >> 4; m0 = (mi & 15) * BM; n0 = (j >> 3) * BN;
    } else {
        z = blockIdx.z; m0 = blockIdx.y * BM; n0 = blockIdx.x * BN;
    }

    const unsigned short* A;
    const unsigned short* B;
    if constexpr (MODE == 0)      { A = Abase + (size_t)z * bnc; B = Bbase; }
    else if constexpr (MODE == 1) { A = Abase; B = Bbase + (size_t)z * bnc; }
    else if constexpr (MODE == 2) { A = Abase + (size_t)z * bnc; B = Bbase + (size_t)z * bnc; }
    else                          { A = Abase; B = Bbase + (size_t)z * bnc; }

    __shared__ __attribute__((aligned(16))) unsigned short As[3][BM * 32];
    __shared__ __attribute__((aligned(16))) unsigned short Bs[3][BN * 32];

    const int t = threadIdx.x;
    const int lane = t & 63;
    const int w = t >> 6;
    const int wr = w >> 1, wc = w & 1;

    // staging: one gload round = 256 threads x 16B = 64 rows x 32 cols.
    const int sr = w * 16 + (lane >> 2);                    // row in 64-row slab
    const int scs = ((lane & 3) ^ ((lane >> 3) & 3)) * 8;   // pre-swizzled col
    const int lds_elem = w * 512;
    const int kslot = lane >> 4;

    floatx4 acc[FI][FJ] = {};

    auto stage = [&](int buf, int tile) {
        const int k0 = tile * 32;
#pragma unroll
        for (int s = 0; s < BM / 64; ++s)
            gload_lds16(A + (size_t)(m0 + s * 64 + sr) * KD + k0 + scs,
                        &As[buf][s * 2048 + lds_elem]);
#pragma unroll
        for (int s = 0; s < BN / 64; ++s)
            gload_lds16(B + (size_t)(n0 + s * 64 + sr) * KD + k0 + scs,
                        &Bs[buf][s * 2048 + lds_elem]);
    };

    auto ds_frags = [&](int buf, bf16x8* af, bf16x8* bfr) {
#pragma unroll
        for (int i = 0; i < FI; ++i) {
            const int ra = wr * (BM / 2) + i * 16 + (lane & 15);
            af[i] = *(const bf16x8*)(&As[buf][ra * 32 + ((kslot ^ ((ra >> 1) & 3)) * 8)]);
        }
#pragma unroll
        for (int j = 0; j < FJ; ++j) {
            const int rb = wc * (BN / 2) + j * 16 + (lane & 15);
            bfr[j] = *(const bf16x8*)(&Bs[buf][rb * 32 + ((kslot ^ ((rb >> 1) & 3)) * 8)]);
        }
    };

    auto mfma_all = [&](const bf16x8* af, const bf16x8* bfr) {
        __builtin_amdgcn_s_setprio(1);
#pragma unroll
        for (int i = 0; i < FI; ++i)
#pragma unroll
            for (int j = 0; j < FJ; ++j)
                acc[i][j] = __builtin_amdgcn_mfma_f32_16x16x32_bf16(
                    af[i], bfr[j], acc[i][j], 0, 0, 0);
        __builtin_amdgcn_s_setprio(0);
    };

    bf16x8 afA[FI], bfA[FJ], afB[FI], bfB[FJ];

    // ---- prologue: 2 tiles in flight, read step-0 operands ----
    stage(0, 0);
    stage(1, 1);
    wait_vmcnt<LPS>();                 // tile 0 landed (tile 1 in flight)
    __builtin_amdgcn_s_barrier();
    ds_frags(0, afA, bfA);

    // ---- main loop: NT-2 iterations, unrolled by 2 (ping-pong A/B) ----
    // iter kt: stage tile kt+2; read step kt+1 frags (LDS-resident) WHILE
    // MFMAs for step kt execute on the other register set.
#pragma unroll
    for (int kp = 0; kp < (NT - 2) / 2; ++kp) {
        const int kt = kp * 2;
        stage((kt + 2) % 3, kt + 2);
        wait_vmcnt<LPS>();             // tile kt+1 landed
        ds_frags((kt + 1) % 3, afB, bfB);
        mfma_all(afA, bfA);
        asm volatile("s_waitcnt lgkmcnt(0)" ::: "memory");
        __builtin_amdgcn_s_barrier();

        stage((kt + 3) % 3, kt + 3);
        wait_vmcnt<LPS>();             // tile kt+2 landed
        ds_frags((kt + 2) % 3, afA, bfA);
        mfma_all(afB, bfB);
        asm volatile("s_waitcnt lgkmcnt(0)" ::: "memory");
        __builtin_amdgcn_s_barrier();
    }

    // ---- tail: steps NT-2 (in A-set) and NT-1 ----
    wait_vmcnt<0>();
    ds_frags((NT - 1) % 3, afB, bfB);
    mfma_all(afA, bfA);
    asm volatile("s_waitcnt lgkmcnt(0)" ::: "memory");
    mfma_all(afB, bfB);

    // ---- Epilogue. C/D: col = lane&15, row = (lane>>4)*4 + reg ----
    const int fr = lane >> 4;
    const int fc = lane & 15;

    if constexpr (MODE == 2) {
        // exp + truncated bf16 store + per-row sum (16-lane reduce + atomicAdd)
        float rs[FI][4];
#pragma unroll
        for (int i = 0; i < FI; ++i)
#pragma unroll
            for (int r = 0; r < 4; ++r) rs[i][r] = 0.f;
#pragma unroll
        for (int i = 0; i < FI; ++i) {
#pragma unroll
            for (int j = 0; j < FJ; ++j) {
                int n = n0 + wc * (BN / 2) + j * 16 + fc;
                int mbase = m0 + wr * (BM / 2) + i * 16 + fr * 4;
#pragma unroll
                for (int r = 0; r < 4; ++r) {
                    float e = __expf(acc[i][j][r]);
                    ob0[(size_t)z * bss + (size_t)(mbase + r) * NN + n] = f2bf_trunc(e);
                    rs[i][r] += e;
                }
            }
        }
#pragma unroll
        for (int i = 0; i < FI; ++i) {
#pragma unroll
            for (int r = 0; r < 4; ++r) {
                float v = rs[i][r];
                v += __shfl_xor(v, 1, 16);
                v += __shfl_xor(v, 2, 16);
                v += __shfl_xor(v, 4, 16);
                v += __shfl_xor(v, 8, 16);
                if (fc == 0) {
                    int m = m0 + wr * (BM / 2) + i * 16 + fr * 4 + r;
                    atomicAdd(&outf[z * NN + m], v);
                }
            }
        }
        return;
    }

#pragma unroll
    for (int i = 0; i < FI; ++i) {
#pragma unroll
        for (int j = 0; j < FJ; ++j) {
            int n = n0 + wc * (BN / 2) + j * 16 + fc;
            int mbase = m0 + wr * (BM / 2) + i * 16 + fr * 4;
#pragma unroll
            for (int r = 0; r < 4; ++r) {
                int m = mbase + r;
                float val = acc[i][j][r];
                if constexpr (MODE == 0) {
                    val += e0[n];   // qkv bias, o = n in [0,1024)
                    if (n < 512) ob0[((size_t)z * NN + m) * NC + n] = f2bf(val * ATTN_SCALE);
                    else         ob1[((size_t)z * NN + m) * NC + (n - 512)] = f2bf(val);
                } else if constexpr (MODE == 1) {
                    val += e0[1024 + m];   // v bias, channel = m
                    ob0[((size_t)z * NC + m) * NN + n] = f2bf(val);
                } else {   // MODE 4
                    size_t idx = ((size_t)z * NC + m) * NN + n;
                    outf[idx] = val + e0[m] + e1[idx];
                }
            }
        }
    }
}

// ---------------------------------------------------------------------------
// PV GEMM: O[p,c] = (sum_m P[p,m] * V[m,c]) / L[p]
// r5 version (BM=128 x BN=128, wave tile 64x64, BK=64 full-line SP rows,
// dbuf prefetch, 2 blk/CU, XCD decode). Not in top-5 at r5 -- unchanged.
// ---------------------------------------------------------------------------
__global__ __launch_bounds__(256, 2) void pv_gemm(
    const unsigned short* __restrict__ Abase,
    const unsigned short* __restrict__ Bbase,
    const float* __restrict__ L,
    unsigned short* __restrict__ Ob)
{
    const int id = blockIdx.x;
    const int xcd = id & 7;
    const int j0 = id >> 3;          // [0,64)
    const int ct = j0 & 3;           // c-tile 0..3 (fastest -> same XCD)
    const int p = (j0 >> 2) * 8 + xcd;   // [0,128) bijective
    const int ptile = p & 31, z = p >> 5;

    const size_t bss = (size_t)NN * NN, bnc = (size_t)NN * NC;
    const unsigned short* A = Abase + (size_t)z * bss;   // SP: (p, m)
    const unsigned short* B = Bbase + (size_t)z * bnc;   // V^T: (c, m)
    const int m0 = ptile * 128;
    const int n0 = ct * 128;

    __shared__ __attribute__((aligned(16))) unsigned short As[2][128 * 64];  // 32 KB
    __shared__ __attribute__((aligned(16))) unsigned short Bs[2][128 * 64];  // 32 KB

    const int t = threadIdx.x;
    const int lane = t & 63;
    const int w = t >> 6;
    const int wr = w >> 1, wc = w & 1;

    // staging: one gload round = 256 threads x 16B = 32 rows x 64 cols.
    const int sr = w * 8 + (lane >> 3);
    const int scs = ((lane & 7) ^ (lane >> 3)) * 8;   // pre-swizzled col (elems)
    const int lds_elem = w * 512;

    floatx4 acc[4][4] = {};

    auto stage = [&](int buf, int k0) {
#pragma unroll
        for (int s = 0; s < 4; ++s)
            gload_lds16(A + (size_t)(m0 + s * 32 + sr) * NN + k0 + scs,
                        &As[buf][s * 2048 + lds_elem]);
#pragma unroll
        for (int s = 0; s < 4; ++s)
            gload_lds16(B + (size_t)(n0 + s * 32 + sr) * NN + k0 + scs,
                        &Bs[buf][s * 2048 + lds_elem]);
    };

    auto compute = [&](int buf) {
#pragma unroll
        for (int kk = 0; kk < 2; ++kk) {
            bf16x8 af[4], bfr[4];
#pragma unroll
            for (int i = 0; i < 4; ++i) {
                const int ra = wr * 64 + i * 16 + (lane & 15);
                af[i] = *(const bf16x8*)(&As[buf][ra * 64 +
                        (((kk * 4 + (lane >> 4)) ^ (ra & 7)) * 8)]);
            }
#pragma unroll
            for (int jf = 0; jf < 4; ++jf) {
                const int rb = wc * 64 + jf * 16 + (lane & 15);
                bfr[jf] = *(const bf16x8*)(&Bs[buf][rb * 64 +
                        (((kk * 4 + (lane >> 4)) ^ (rb & 7)) * 8)]);
            }
#pragma unroll
            for (int i = 0; i < 4; ++i)
#pragma unroll
                for (int jf = 0; jf < 4; ++jf)
                    acc[i][jf] = __builtin_amdgcn_mfma_f32_16x16x32_bf16(
                        af[i], bfr[jf], acc[i][jf], 0, 0, 0);
        }
    };

    stage(0, 0);
    asm volatile("s_waitcnt vmcnt(0)" ::: "memory");
    __builtin_amdgcn_s_barrier();
    for (int kc = 0; kc < 63; ++kc) {
        stage((kc + 1) & 1, (kc + 1) * 64);   // prefetch next chunk (async)
        compute(kc & 1);
        asm volatile("s_waitcnt lgkmcnt(0)" ::: "memory");
        asm volatile("s_waitcnt vmcnt(0)" ::: "memory");
        __builtin_amdgcn_s_barrier();
    }
    compute(1);

    const int fr = lane >> 4;
    const int fc = lane & 15;
#pragma unroll
    for (int i = 0; i < 4; ++i) {
#pragma unroll
        for (int r = 0; r < 4; ++r) {
            int m = m0 + wr * 64 + i * 16 + fr * 4 + r;
            float linv = 1.0f / L[z * NN + m];
#pragma unroll
            for (int jf = 0; jf < 4; ++jf) {
                int n = n0 + wc * 64 + jf * 16 + fc;
                Ob[(size_t)z * bnc + (size_t)m * NC + n] = f2bf(acc[i][jf][r] * linv);
            }
        }
    }
}

// ---------------------------------------------------------------------------
extern "C" void kernel_launch(void* const* d_in, const int* in_sizes, int n_in,
                              void* d_out, int out_size, void* d_ws, size_t ws_size,
                              hipStream_t stream)
{
    const float* x     = (const float*)d_in[0];
    const float* gn_w  = (const float*)d_in[1];
    const float* gn_b  = (const float*)d_in[2];
    const float* qkv_w = (const float*)d_in[3];
    const float* qkv_b = (const float*)d_in[4];
    const float* out_w = (const float*)d_in[5];
    const float* out_b = (const float*)d_in[6];
    float* out = (float*)d_out;

    const size_t bnc = (size_t)NN * NC;          // 2,097,152 per batch
    char* w = (char*)d_ws;
    float* ss   = (float*)w;                 w += 16384;
    float* part = (float*)w;                 w += 8192;
    float* Lsum = (float*)w;                 w += (size_t)NB * NN * 4;  // row sums
    unsigned short* wq = (unsigned short*)w; w += (size_t)1536 * 512 * 2;
    unsigned short* wo = (unsigned short*)w; w += (size_t)512 * 512 * 2;
    unsigned short* qt = (unsigned short*)w; w += NB * bnc * 2;   // (b,n,c) pre-scaled
    unsigned short* kt = (unsigned short*)w; w += NB * bnc * 2;   // (b,n,c)
    unsigned short* vt = (unsigned short*)w; w += NB * bnc * 2;   // (b,c,n)
    unsigned short* SP = (unsigned short*)w; w += (size_t)NB * NN * NN * 2; // 128 MB
    // Aliases (lifetime-disjoint):
    unsigned short* ht = SP;   // ht (b,n,c) dead before MODE 2 writes SP
    unsigned short* Ob = qt;   // Ob (b,n,c) written after qt last read (MODE 2)

    hipMemsetAsync(Lsum, 0, (size_t)NB * NN * sizeof(float), stream);

    gn_partial_kernel<<<1024, 256, 0, stream>>>(x, part);
    gn_final_kernel<<<1, 128, 0, stream>>>(part, gn_w, gn_b, ss);
    wconv_kernel<<<(1536 * 512 + 512 * 512) / 256, 256, 0, stream>>>(qkv_w, out_w, wq, wo);
    htnorm_kernel<<<dim3(NN / 32, NC / 32, NB), 256, 0, stream>>>(x, ss, ht);

    // q/k: C[p,o] = ht · wqk^T   (q pre-scaled by ATTN_SCALE)
    mfma_gemm<0, 128, 128, 512, 2><<<dim3(1024 / 128, NN / 128, NB), 256, 0, stream>>>(
        ht, wq, qkv_b, nullptr, nullptr, qt, kt);
    // v: C[c,p] = wv · ht^T   (64x128 tile -> 1024 blocks = 4/CU)
    mfma_gemm<1, 64, 128, 512, 4><<<dim3(NN / 128, 512 / 64, NB), 256, 0, stream>>>(
        wq + (size_t)1024 * 512, ht, qkv_b, nullptr, nullptr, vt, nullptr);

    // QK^T + exp + row-sum; BM=256 wave-tile 128x64, 2048 blocks, XCD-decoded
    mfma_gemm<2, 256, 128, 512, 2><<<dim3(2048), 256, 0, stream>>>(
        qt, kt, nullptr, nullptr, Lsum, SP, nullptr);
    // PV + normalize; BM=128xBN=128 wave-tile 64x64, 512 blocks, XCD-decoded
    pv_gemm<<<dim3(512), 256, 0, stream>>>(SP, vt, Lsum, Ob);

    // out projection + bias + residual (64x128 tile -> 1024 blocks = 4/CU)
    mfma_gemm<4, 64, 128, 512, 4><<<dim3(NN / 128, 512 / 64, NB), 256, 0, stream>>>(
        wo, Ob, out_b, x, out, nullptr, nullptr);
}

// Round 7
// 342.811 us; speedup vs baseline: 1.2196x; 1.0299x over previous
//
#include <hip/hip_runtime.h>
#include <cmath>

// b=4, c=512, h=w=64 -> n=4096, groups=32 (16 ch/group)
#define NB 4
#define NC 512
#define NN 4096
#define ATTN_SCALE 0.04419417382415922f  // 512^-0.5

typedef __bf16 bf16x8 __attribute__((ext_vector_type(8)));
typedef float floatx4 __attribute__((ext_vector_type(4)));

__device__ __forceinline__ unsigned short f2bf(float f) {
    union { float f; unsigned int u; } v; v.f = f;
    return (unsigned short)((v.u + 0x7fffu + ((v.u >> 16) & 1u)) >> 16);
}
__device__ __forceinline__ unsigned short f2bf_trunc(float f) {
    union { float f; unsigned int u; } v; v.f = f;
    return (unsigned short)(v.u >> 16);
}

__device__ __forceinline__ void gload_lds16(const unsigned short* gp, unsigned short* lp) {
    __builtin_amdgcn_global_load_lds(
        (const __attribute__((address_space(1))) void*)gp,
        (__attribute__((address_space(3))) void*)lp, 16, 0, 0);
}

template<int N> __device__ __forceinline__ void wait_vmcnt() {
    if constexpr (N == 0) asm volatile("s_waitcnt vmcnt(0)" ::: "memory");
    else if constexpr (N == 2) asm volatile("s_waitcnt vmcnt(2)" ::: "memory");
    else if constexpr (N == 3) asm volatile("s_waitcnt vmcnt(3)" ::: "memory");
    else if constexpr (N == 4) asm volatile("s_waitcnt vmcnt(4)" ::: "memory");
    else if constexpr (N == 6) asm volatile("s_waitcnt vmcnt(6)" ::: "memory");
}

// ---------------------------------------------------------------------------
// Kernel 1a: GroupNorm partial sums. 1024 blocks = (b,g) x 8 slices.
// ---------------------------------------------------------------------------
__global__ __launch_bounds__(256) void gn_partial_kernel(
    const float* __restrict__ x, float* __restrict__ part)
{
    int blk = blockIdx.x;
    int bg = blk >> 3, sub = blk & 7;
    const float4* xv = (const float4*)(x + (size_t)bg * 16 * NN + (size_t)sub * 8192);
    float s1 = 0.f, s2 = 0.f;
#pragma unroll
    for (int i = 0; i < 8; ++i) {
        float4 v = xv[threadIdx.x + i * 256];
        s1 += v.x + v.y + v.z + v.w;
        s2 += v.x * v.x + v.y * v.y + v.z * v.z + v.w * v.w;
    }
#pragma unroll
    for (int off = 32; off; off >>= 1) {
        s1 += __shfl_xor(s1, off, 64);
        s2 += __shfl_xor(s2, off, 64);
    }
    __shared__ float r1[4], r2[4];
    int lane = threadIdx.x & 63, w = threadIdx.x >> 6;
    if (lane == 0) { r1[w] = s1; r2[w] = s2; }
    __syncthreads();
    if (threadIdx.x == 0) {
        part[blk * 2]     = r1[0] + r1[1] + r1[2] + r1[3];
        part[blk * 2 + 1] = r2[0] + r2[1] + r2[2] + r2[3];
    }
}

// Kernel 1b: finalize -> per-channel scale/shift
__global__ __launch_bounds__(128) void gn_final_kernel(
    const float* __restrict__ part, const float* __restrict__ gw,
    const float* __restrict__ gb, float* __restrict__ ss)
{
    int tg = threadIdx.x;            // 0..127 = b*32+g
    int b = tg >> 5, g = tg & 31;
    float s1 = 0.f, s2 = 0.f;
#pragma unroll
    for (int s = 0; s < 8; ++s) {
        s1 += part[(tg * 8 + s) * 2];
        s2 += part[(tg * 8 + s) * 2 + 1];
    }
    float mean = s1 * (1.0f / 65536.0f);
    float var  = s2 * (1.0f / 65536.0f) - mean * mean;
    float rstd = rsqrtf(var + 1e-5f);
#pragma unroll
    for (int i = 0; i < 16; ++i) {
        int c = g * 16 + i;
        float sc = rstd * gw[c];
        ss[b * NC + c] = sc;
        ss[2048 + b * NC + c] = gb[c] - mean * sc;
    }
}

// ---------------------------------------------------------------------------
// Kernel 2: convert weights fp32 -> bf16
// ---------------------------------------------------------------------------
__global__ __launch_bounds__(256) void wconv_kernel(
    const float* __restrict__ qkv_w, const float* __restrict__ out_w,
    unsigned short* __restrict__ wq, unsigned short* __restrict__ wo)
{
    int i = blockIdx.x * 256 + threadIdx.x;
    const int NQ = 1536 * 512;
    if (i < NQ) wq[i] = f2bf(qkv_w[i]);
    else        wo[i - NQ] = f2bf(out_w[i - NQ]);
}

// ---------------------------------------------------------------------------
// Kernel 3: normalize + transpose: x (b,c,n) fp32 -> h_t (b,n,c) bf16
// ---------------------------------------------------------------------------
__global__ __launch_bounds__(256) void htnorm_kernel(
    const float* __restrict__ x, const float* __restrict__ ss,
    unsigned short* __restrict__ ht)
{
    int b = blockIdx.z;
    int c0 = blockIdx.y * 32, n0 = blockIdx.x * 32;
    __shared__ float T[32][33];
    int tx = threadIdx.x & 31, ty = threadIdx.x >> 5;   // ty 0..7
    const float* xb = x + ((size_t)b * NC + c0) * NN;
    const float* sc = ss + b * NC + c0;
    const float* sh = ss + 2048 + b * NC + c0;
#pragma unroll
    for (int i = 0; i < 4; ++i) {
        int c = ty + i * 8;
        T[c][tx] = xb[(size_t)c * NN + n0 + tx] * sc[c] + sh[c];
    }
    __syncthreads();
    unsigned short* hb = ht + ((size_t)b * NN + n0) * NC + c0;
#pragma unroll
    for (int i = 0; i < 4; ++i) {
        int n = ty + i * 8;
        hb[(size_t)n * NC + tx] = f2bf(T[tx][n]);
    }
}

// ---------------------------------------------------------------------------
// MFMA NT GEMM: C[m,n] = sum_k A[m,k]*B[n,k], BK=32, KD=512, NBUF=3.
// Round-7: PIPE variants.
//  PIPE=0 (MODE 2): r5-exact counted-vmcnt loop (proven 109us, proven absmax).
//  PIPE=1 (MODES 0/1/4): corrected cross-barrier reg pipeline. r6's version
//   had a cross-wave race (per-wave vmcnt does not order OTHER waves'
//   global_load_lds writes before my LDS read). Fix: barrier moved to
//   mid-iteration -- stage(kt+2); vmcnt(LPS) [tile kt+1 mine landed];
//   s_barrier [ALL waves' tile kt+1 landed]; ds_frags(kt+1 -> next set)
//   co-issues with mfma(cur set); lgkm0 before the next barrier closes the
//   buffer-reuse window. Register dataflow is compiler-tracked (no rule-18
//   hazard: frag loads are C++ loads, not inline asm).
// MODE 0: qkv q/k   M=4096 N=1024 K=512  A=ht(+z) B=wqk    -> qt(*scale)/kt +bias
// MODE 1: qkv v     M=512  N=4096 K=512  A=wv     B=ht(+z) -> vt (c,p) bf16 +bias
// MODE 2: QK^T      M=4096 N=4096 K=512  A=qt(+z) B=kt(+z) -> SP = exp(s) bf16,
//                   row-sums atomically accumulated into outf = L[b*NN+row]
// MODE 4: out proj  M=512  N=4096 K=512  A=wo     B=Ob(+z) -> out fp32 +bias+res
// ---------------------------------------------------------------------------
template<int MODE, int BM, int BN, int KD, int MINB, int PIPE>
__global__ __launch_bounds__(256, MINB) void mfma_gemm(
    const unsigned short* __restrict__ Abase,
    const unsigned short* __restrict__ Bbase,
    const float* __restrict__ e0, const float* __restrict__ e1,
    float* __restrict__ outf,
    unsigned short* __restrict__ ob0, unsigned short* __restrict__ ob1)
{
    constexpr int NT = KD / 32;       // 16 K-steps (even)
    constexpr int FI = BM / 32;       // frag rows per wave
    constexpr int FJ = BN / 32;       // frag cols per wave
    constexpr int LPS = BM / 64 + BN / 64;   // gloads per thread per stage
    const size_t bnc = (size_t)NN * NC;
    const size_t bss = (size_t)NN * NN;

    int z, m0, n0;
    if constexpr (MODE == 2) {
        // XCD-grouped 1-D decode (grid 2048, rr dispatch): each XCD owns 8
        // m-tiles (2MB qt panel L2-resident), n-tile slow.
        const int id = blockIdx.x;
        const int xcd = id & 7, j = id >> 3;       // j in [0,256)
        const int mi = xcd * 8 + (j & 7);          // [0,64)
        z = mi >> 4; m0 = (mi & 15) * BM; n0 = (j >> 3) * BN;
    } else {
        z = blockIdx.z; m0 = blockIdx.y * BM; n0 = blockIdx.x * BN;
    }

    const unsigned short* A;
    const unsigned short* B;
    if constexpr (MODE == 0)      { A = Abase + (size_t)z * bnc; B = Bbase; }
    else if constexpr (MODE == 1) { A = Abase; B = Bbase + (size_t)z * bnc; }
    else if constexpr (MODE == 2) { A = Abase + (size_t)z * bnc; B = Bbase + (size_t)z * bnc; }
    else                          { A = Abase; B = Bbase + (size_t)z * bnc; }

    __shared__ __attribute__((aligned(16))) unsigned short As[3][BM * 32];
    __shared__ __attribute__((aligned(16))) unsigned short Bs[3][BN * 32];

    const int t = threadIdx.x;
    const int lane = t & 63;
    const int w = t >> 6;
    const int wr = w >> 1, wc = w & 1;

    // staging: one gload round = 256 threads x 16B = 64 rows x 32 cols.
    const int sr = w * 16 + (lane >> 2);                    // row in 64-row slab
    const int scs = ((lane & 3) ^ ((lane >> 3) & 3)) * 8;   // pre-swizzled col
    const int lds_elem = w * 512;
    const int kslot = lane >> 4;

    floatx4 acc[FI][FJ] = {};

    auto stage = [&](int buf, int tile) {
        const int k0 = tile * 32;
#pragma unroll
        for (int s = 0; s < BM / 64; ++s)
            gload_lds16(A + (size_t)(m0 + s * 64 + sr) * KD + k0 + scs,
                        &As[buf][s * 2048 + lds_elem]);
#pragma unroll
        for (int s = 0; s < BN / 64; ++s)
            gload_lds16(B + (size_t)(n0 + s * 64 + sr) * KD + k0 + scs,
                        &Bs[buf][s * 2048 + lds_elem]);
    };

    auto ds_frags = [&](int buf, bf16x8* af, bf16x8* bfr) {
#pragma unroll
        for (int i = 0; i < FI; ++i) {
            const int ra = wr * (BM / 2) + i * 16 + (lane & 15);
            af[i] = *(const bf16x8*)(&As[buf][ra * 32 + ((kslot ^ ((ra >> 1) & 3)) * 8)]);
        }
#pragma unroll
        for (int j = 0; j < FJ; ++j) {
            const int rb = wc * (BN / 2) + j * 16 + (lane & 15);
            bfr[j] = *(const bf16x8*)(&Bs[buf][rb * 32 + ((kslot ^ ((rb >> 1) & 3)) * 8)]);
        }
    };

    auto mfma_all = [&](const bf16x8* af, const bf16x8* bfr) {
#pragma unroll
        for (int i = 0; i < FI; ++i)
#pragma unroll
            for (int j = 0; j < FJ; ++j)
                acc[i][j] = __builtin_amdgcn_mfma_f32_16x16x32_bf16(
                    af[i], bfr[j], acc[i][j], 0, 0, 0);
    };

    if constexpr (PIPE == 0) {
        // ---- r5-exact counted-vmcnt loop (DEPTH=2) ----
        bf16x8 af[FI], bfr[FJ];
        stage(0, 0);
        stage(1, 1);
        wait_vmcnt<LPS>();
        __builtin_amdgcn_s_barrier();
#pragma unroll
        for (int kt = 0; kt < NT - 2; ++kt) {
            stage((kt + 2) % 3, kt + 2);
            ds_frags(kt % 3, af, bfr);
            mfma_all(af, bfr);
            asm volatile("s_waitcnt lgkmcnt(0)" ::: "memory");
            wait_vmcnt<LPS>();
            __builtin_amdgcn_s_barrier();
        }
        ds_frags((NT - 2) % 3, af, bfr);
        mfma_all(af, bfr);
        asm volatile("s_waitcnt lgkmcnt(0)" ::: "memory");
        wait_vmcnt<0>();
        __builtin_amdgcn_s_barrier();
        ds_frags((NT - 1) % 3, af, bfr);
        mfma_all(af, bfr);
    } else {
        // ---- corrected cross-barrier reg pipeline (ping-pong sets) ----
        bf16x8 afA[FI], bfA[FJ], afB[FI], bfB[FJ];
        stage(0, 0);
        stage(1, 1);
        wait_vmcnt<LPS>();                 // tile 0 landed (mine)
        __builtin_amdgcn_s_barrier();      // tile 0 landed (all waves)
        ds_frags(0, afA, bfA);
        asm volatile("s_waitcnt lgkmcnt(0)" ::: "memory");
#pragma unroll
        for (int kp = 0; kp < (NT - 2) / 2; ++kp) {
            const int kt = kp * 2;
            // step kt: compute set A, read tile kt+1 into set B
            stage((kt + 2) % 3, kt + 2);
            wait_vmcnt<LPS>();             // tile kt+1 landed (mine)
            __builtin_amdgcn_s_barrier();  // tile kt+1 landed (all)
            ds_frags((kt + 1) % 3, afB, bfB);
            mfma_all(afA, bfA);
            asm volatile("s_waitcnt lgkmcnt(0)" ::: "memory");
            // step kt+1: compute set B, read tile kt+2 into set A
            stage((kt + 3) % 3, kt + 3);
            wait_vmcnt<LPS>();             // tile kt+2 landed (mine)
            __builtin_amdgcn_s_barrier();  // tile kt+2 landed (all)
            ds_frags((kt + 2) % 3, afA, bfA);
            mfma_all(afB, bfB);
            asm volatile("s_waitcnt lgkmcnt(0)" ::: "memory");
        }
        // tail: steps NT-2 (set A) and NT-1
        wait_vmcnt<0>();                   // tile NT-1 landed (mine)
        __builtin_amdgcn_s_barrier();      // tile NT-1 landed (all)
        ds_frags((NT - 1) % 3, afB, bfB);
        mfma_all(afA, bfA);
        asm volatile("s_waitcnt lgkmcnt(0)" ::: "memory");
        mfma_all(afB, bfB);
    }

    // ---- Epilogue. C/D: col = lane&15, row = (lane>>4)*4 + reg ----
    const int fr = lane >> 4;
    const int fc = lane & 15;

    if constexpr (MODE == 2) {
        // exp + truncated bf16 store + per-row sum (16-lane reduce + atomicAdd)
        float rs[FI][4];
#pragma unroll
        for (int i = 0; i < FI; ++i)
#pragma unroll
            for (int r = 0; r < 4; ++r) rs[i][r] = 0.f;
#pragma unroll
        for (int i = 0; i < FI; ++i) {
#pragma unroll
            for (int j = 0; j < FJ; ++j) {
                int n = n0 + wc * (BN / 2) + j * 16 + fc;
                int mbase = m0 + wr * (BM / 2) + i * 16 + fr * 4;
#pragma unroll
                for (int r = 0; r < 4; ++r) {
                    float e = __expf(acc[i][j][r]);
                    ob0[(size_t)z * bss + (size_t)(mbase + r) * NN + n] = f2bf_trunc(e);
                    rs[i][r] += e;
                }
            }
        }
#pragma unroll
        for (int i = 0; i < FI; ++i) {
#pragma unroll
            for (int r = 0; r < 4; ++r) {
                float v = rs[i][r];
                v += __shfl_xor(v, 1, 16);
                v += __shfl_xor(v, 2, 16);
                v += __shfl_xor(v, 4, 16);
                v += __shfl_xor(v, 8, 16);
                if (fc == 0) {
                    int m = m0 + wr * (BM / 2) + i * 16 + fr * 4 + r;
                    atomicAdd(&outf[z * NN + m], v);
                }
            }
        }
        return;
    }

#pragma unroll
    for (int i = 0; i < FI; ++i) {
#pragma unroll
        for (int j = 0; j < FJ; ++j) {
            int n = n0 + wc * (BN / 2) + j * 16 + fc;
            int mbase = m0 + wr * (BM / 2) + i * 16 + fr * 4;
#pragma unroll
            for (int r = 0; r < 4; ++r) {
                int m = mbase + r;
                float val = acc[i][j][r];
                if constexpr (MODE == 0) {
                    val += e0[n];   // qkv bias, o = n in [0,1024)
                    if (n < 512) ob0[((size_t)z * NN + m) * NC + n] = f2bf(val * ATTN_SCALE);
                    else         ob1[((size_t)z * NN + m) * NC + (n - 512)] = f2bf(val);
                } else if constexpr (MODE == 1) {
                    val += e0[1024 + m];   // v bias, channel = m
                    ob0[((size_t)z * NC + m) * NN + n] = f2bf(val);
                } else {   // MODE 4
                    size_t idx = ((size_t)z * NC + m) * NN + n;
                    outf[idx] = val + e0[m] + e1[idx];
                }
            }
        }
    }
}

// ---------------------------------------------------------------------------
// PV GEMM: O[p,c] = (sum_m P[p,m] * V[m,c]) / L[p]
// r5 version (BM=128 x BN=128, wave tile 64x64, BK=64 full-line SP rows,
// dbuf prefetch, 2 blk/CU, XCD decode). Unchanged.
// ---------------------------------------------------------------------------
__global__ __launch_bounds__(256, 2) void pv_gemm(
    const unsigned short* __restrict__ Abase,
    const unsigned short* __restrict__ Bbase,
    const float* __restrict__ L,
    unsigned short* __restrict__ Ob)
{
    const int id = blockIdx.x;
    const int xcd = id & 7;
    const int j0 = id >> 3;          // [0,64)
    const int ct = j0 & 3;           // c-tile 0..3 (fastest -> same XCD)
    const int p = (j0 >> 2) * 8 + xcd;   // [0,128) bijective
    const int ptile = p & 31, z = p >> 5;

    const size_t bss = (size_t)NN * NN, bnc = (size_t)NN * NC;
    const unsigned short* A = Abase + (size_t)z * bss;   // SP: (p, m)
    const unsigned short* B = Bbase + (size_t)z * bnc;   // V^T: (c, m)
    const int m0 = ptile * 128;
    const int n0 = ct * 128;

    __shared__ __attribute__((aligned(16))) unsigned short As[2][128 * 64];  // 32 KB
    __shared__ __attribute__((aligned(16))) unsigned short Bs[2][128 * 64];  // 32 KB

    const int t = threadIdx.x;
    const int lane = t & 63;
    const int w = t >> 6;
    const int wr = w >> 1, wc = w & 1;

    // staging: one gload round = 256 threads x 16B = 32 rows x 64 cols.
    const int sr = w * 8 + (lane >> 3);
    const int scs = ((lane & 7) ^ (lane >> 3)) * 8;   // pre-swizzled col (elems)
    const int lds_elem = w * 512;

    floatx4 acc[4][4] = {};

    auto stage = [&](int buf, int k0) {
#pragma unroll
        for (int s = 0; s < 4; ++s)
            gload_lds16(A + (size_t)(m0 + s * 32 + sr) * NN + k0 + scs,
                        &As[buf][s * 2048 + lds_elem]);
#pragma unroll
        for (int s = 0; s < 4; ++s)
            gload_lds16(B + (size_t)(n0 + s * 32 + sr) * NN + k0 + scs,
                        &Bs[buf][s * 2048 + lds_elem]);
    };

    auto compute = [&](int buf) {
#pragma unroll
        for (int kk = 0; kk < 2; ++kk) {
            bf16x8 af[4], bfr[4];
#pragma unroll
            for (int i = 0; i < 4; ++i) {
                const int ra = wr * 64 + i * 16 + (lane & 15);
                af[i] = *(const bf16x8*)(&As[buf][ra * 64 +
                        (((kk * 4 + (lane >> 4)) ^ (ra & 7)) * 8)]);
            }
#pragma unroll
            for (int jf = 0; jf < 4; ++jf) {
                const int rb = wc * 64 + jf * 16 + (lane & 15);
                bfr[jf] = *(const bf16x8*)(&Bs[buf][rb * 64 +
                        (((kk * 4 + (lane >> 4)) ^ (rb & 7)) * 8)]);
            }
#pragma unroll
            for (int i = 0; i < 4; ++i)
#pragma unroll
                for (int jf = 0; jf < 4; ++jf)
                    acc[i][jf] = __builtin_amdgcn_mfma_f32_16x16x32_bf16(
                        af[i], bfr[jf], acc[i][jf], 0, 0, 0);
        }
    };

    stage(0, 0);
    asm volatile("s_waitcnt vmcnt(0)" ::: "memory");
    __builtin_amdgcn_s_barrier();
    for (int kc = 0; kc < 63; ++kc) {
        stage((kc + 1) & 1, (kc + 1) * 64);   // prefetch next chunk (async)
        compute(kc & 1);
        asm volatile("s_waitcnt lgkmcnt(0)" ::: "memory");
        asm volatile("s_waitcnt vmcnt(0)" ::: "memory");
        __builtin_amdgcn_s_barrier();
    }
    compute(1);

    const int fr = lane >> 4;
    const int fc = lane & 15;
#pragma unroll
    for (int i = 0; i < 4; ++i) {
#pragma unroll
        for (int r = 0; r < 4; ++r) {
            int m = m0 + wr * 64 + i * 16 + fr * 4 + r;
            float linv = 1.0f / L[z * NN + m];
#pragma unroll
            for (int jf = 0; jf < 4; ++jf) {
                int n = n0 + wc * 64 + jf * 16 + fc;
                Ob[(size_t)z * bnc + (size_t)m * NC + n] = f2bf(acc[i][jf][r] * linv);
            }
        }
    }
}

// ---------------------------------------------------------------------------
extern "C" void kernel_launch(void* const* d_in, const int* in_sizes, int n_in,
                              void* d_out, int out_size, void* d_ws, size_t ws_size,
                              hipStream_t stream)
{
    const float* x     = (const float*)d_in[0];
    const float* gn_w  = (const float*)d_in[1];
    const float* gn_b  = (const float*)d_in[2];
    const float* qkv_w = (const float*)d_in[3];
    const float* qkv_b = (const float*)d_in[4];
    const float* out_w = (const float*)d_in[5];
    const float* out_b = (const float*)d_in[6];
    float* out = (float*)d_out;

    const size_t bnc = (size_t)NN * NC;          // 2,097,152 per batch
    char* w = (char*)d_ws;
    float* ss   = (float*)w;                 w += 16384;
    float* part = (float*)w;                 w += 8192;
    float* Lsum = (float*)w;                 w += (size_t)NB * NN * 4;  // row sums
    unsigned short* wq = (unsigned short*)w; w += (size_t)1536 * 512 * 2;
    unsigned short* wo = (unsigned short*)w; w += (size_t)512 * 512 * 2;
    unsigned short* qt = (unsigned short*)w; w += NB * bnc * 2;   // (b,n,c) pre-scaled
    unsigned short* kt = (unsigned short*)w; w += NB * bnc * 2;   // (b,n,c)
    unsigned short* vt = (unsigned short*)w; w += NB * bnc * 2;   // (b,c,n)
    unsigned short* SP = (unsigned short*)w; w += (size_t)NB * NN * NN * 2; // 128 MB
    // Aliases (lifetime-disjoint):
    unsigned short* ht = SP;   // ht (b,n,c) dead before MODE 2 writes SP
    unsigned short* Ob = qt;   // Ob (b,n,c) written after qt last read (MODE 2)

    hipMemsetAsync(Lsum, 0, (size_t)NB * NN * sizeof(float), stream);

    gn_partial_kernel<<<1024, 256, 0, stream>>>(x, part);
    gn_final_kernel<<<1, 128, 0, stream>>>(part, gn_w, gn_b, ss);
    wconv_kernel<<<(1536 * 512 + 512 * 512) / 256, 256, 0, stream>>>(qkv_w, out_w, wq, wo);
    htnorm_kernel<<<dim3(NN / 32, NC / 32, NB), 256, 0, stream>>>(x, ss, ht);

    // q/k: C[p,o] = ht · wqk^T   (q pre-scaled by ATTN_SCALE), PIPE=1, 2 blk/CU
    mfma_gemm<0, 128, 128, 512, 2, 1><<<dim3(1024 / 128, NN / 128, NB), 256, 0, stream>>>(
        ht, wq, qkv_b, nullptr, nullptr, qt, kt);
    // v: C[c,p] = wv · ht^T   (64x128 tile, PIPE=1, 4 blk/CU)
    mfma_gemm<1, 64, 128, 512, 4, 1><<<dim3(NN / 128, 512 / 64, NB), 256, 0, stream>>>(
        wq + (size_t)1024 * 512, ht, qkv_b, nullptr, nullptr, vt, nullptr);

    // QK^T + exp + row-sum; BM=256 wave-tile 128x64, PIPE=0 (r5-exact), XCD-decoded
    mfma_gemm<2, 256, 128, 512, 2, 0><<<dim3(2048), 256, 0, stream>>>(
        qt, kt, nullptr, nullptr, Lsum, SP, nullptr);
    // PV + normalize; BM=128xBN=128 wave-tile 64x64, 512 blocks, XCD-decoded
    pv_gemm<<<dim3(512), 256, 0, stream>>>(SP, vt, Lsum, Ob);

    // out projection + bias + residual (64x128 tile, PIPE=1, 4 blk/CU)
    mfma_gemm<4, 64, 128, 512, 4, 1><<<dim3(NN / 128, 512 / 64, NB), 256, 0, stream>>>(
        wo, Ob, out_b, x, out, nullptr, nullptr);
}